// Round 5
// baseline (1419.834 us; speedup 1.0000x reference)
//
#include <hip/hip_runtime.h>
#include <hip/hip_bf16.h>

// HGCN forward (2-layer hyperbolic GCN), Poincare ball c=1.
// Round 5 = round 3's PASSED pipeline with exactly ONE change: layer1 is now an
// MFMA GEMM (16x16x32 bf16, wave per 16 nodes, no LDS), self-gated on the dtype
// flag; round 3's wave-per-node layer1 kept as fp32-input fallback.
// Everything else (probe, zero, scatter, layer2, final; fp32 xt in d_out; fp32
// agg + flag in d_ws) is byte-identical to the round-3 passing code.

#define EPSV 1e-15f
#define MAXN 0.996f   // (1 - 4e-3) / sqrt(c), c = 1

typedef unsigned short bfu;
typedef __attribute__((ext_vector_type(8))) short v8s;   // 8 bf16 (4 VGPRs)
typedef __attribute__((ext_vector_type(4))) float v4f;   // MFMA acc

__device__ __forceinline__ float b2f(bfu s) {
    unsigned int u = ((unsigned int)s) << 16;
    float f;
    __builtin_memcpy(&f, &u, sizeof(f));
    return f;
}

// load element idx of a float-ish input: f==0 -> bf16, f==1 -> fp32
__device__ __forceinline__ float ldx(const void* p, size_t idx, int f) {
    return f ? ((const float*)p)[idx] : b2f(((const bfu*)p)[idx]);
}

__device__ __forceinline__ float wredsum(float v) {
#pragma unroll
    for (int o = 32; o > 0; o >>= 1) v += __shfl_xor(v, o, 64);
    return v;  // butterfly: bit-identical across all 64 lanes
}

__device__ __forceinline__ float artanh_(float x) {
    x = fminf(fmaxf(x, -1.0f + 1e-7f), 1.0f - 1e-7f);
    return 0.5f * logf((1.0f + x) / (1.0f - x));
}

__device__ __forceinline__ float mobius_tail(float mx, float xn, float hb, float y2) {
    float mxn2 = wredsum(mx * mx);
    unsigned long long nz = __ballot(mx != 0.0f);
    float mxn = fmaxf(sqrtf(mxn2), EPSV);
    float rt = tanhf(mxn / xn * artanh_(xn));
    float mv, x2s;
    if (nz != 0ull) {
        mv = (rt / mxn) * mx;
        float mvn = fmaxf(fabsf(rt), EPSV);
        if (mvn > MAXN) mv *= MAXN / mvn;
        float cn = fminf(mvn, MAXN);
        x2s = cn * cn;
    } else { mv = 0.0f; x2s = 0.0f; }
    float xy = wredsum(mv * hb);
    float ca = 1.0f + 2.0f * xy + y2;
    float cb = 1.0f - x2s;
    float den = fmaxf(1.0f + 2.0f * xy + x2s * y2, EPSV);
    float hj = (ca * mv + cb * hb) / den;
    float hn = fmaxf(sqrtf(wredsum(hj * hj)), EPSV);
    if (hn > MAXN) { hj *= MAXN / hn; hn = MAXN; }
    return (artanh_(hn) / hn) * hj;
}

__device__ __forceinline__ float agg_transform(float a, float* xn_out) {
    float n = fmaxf(sqrtf(wredsum(a * a)), EPSV);
    float th = tanhf(n);
    float g = th / n;
    float nh = fmaxf(th, EPSV);
    if (nh > MAXN) { g *= MAXN / nh; nh = MAXN; }
    float h = g * a;
    float t = fmaxf((artanh_(nh) / nh) * h, 0.0f);
    float n2 = fmaxf(sqrtf(wredsum(t * t)), EPSV);
    float th2 = tanhf(n2);
    float g2 = th2 / n2;
    float nh2 = fmaxf(th2, EPSV);
    if (nh2 > MAXN) { g2 *= MAXN / nh2; nh2 = MAXN; }
    *xn_out = nh2;
    return g2 * t;
}

__device__ __forceinline__ float bias_point(const void* bv, int lane, int f, float* y2) {
    float b = ldx(bv, lane, f);
    float bn = fmaxf(sqrtf(wredsum(b * b)), EPSV);
    float gs = tanhf(bn) / bn;
    float hbn = fmaxf(tanhf(bn), EPSV);
    if (hbn > MAXN) gs *= MAXN / hbn;
    float hb = gs * b;
    *y2 = wredsum(hb * hb);
    return hb;
}

// ---------- input-dtype probe ----------
__global__ void hg5_probe(const void* b1v, int* flagp) {
    int lane = threadIdx.x & 63;
    float v = b2f(((const bfu*)b1v)[lane]);
    float bad = (fabsf(v) > 1e4f || v != v) ? 1.0f : 0.0f;
    bad = wredsum(bad);
    if (lane == 0) flagp[0] = (bad > 0.0f) ? 1 : 0;
}

__global__ __launch_bounds__(256) void hg5_zero(float* __restrict__ p, int n4) {
    const float4 z = make_float4(0.f, 0.f, 0.f, 0.f);
    int stride = gridDim.x * blockDim.x;
    for (int i = blockIdx.x * blockDim.x + threadIdx.x; i < n4; i += stride)
        ((float4*)p)[i] = z;
}

// ---------- layer 1 (bf16 fast path): MFMA GEMM, wave per 16 nodes ----------
__global__ __launch_bounds__(256) void hg5_layer1_mfma(
    const bfu* __restrict__ x,     // [N,256]
    const bfu* __restrict__ W1,    // [64,256] row-major
    const bfu* __restrict__ b1v,   // [64]
    float* __restrict__ xt, const int* __restrict__ flagp, int N)
{
    if (*flagp != 0) return;       // wave-uniform gate: bf16 inputs only
    const int tid = threadIdx.x, lane = tid & 63, wv = tid >> 6;
    const int nodeBase = (blockIdx.x * 4 + wv) * 16;
    if (nodeBase >= N) return;

    float y2;
    float hb = bias_point(b1v, lane, 0, &y2);      // lane = dim layout
    float hbv[4];
#pragma unroll
    for (int t = 0; t < 4; ++t) hbv[t] = __shfl(hb, (lane & 15) + 16 * t);

    const int m = lane & 15, q = lane >> 4;
    v4f acc0 = {0,0,0,0}, acc1 = {0,0,0,0}, acc2 = {0,0,0,0}, acc3 = {0,0,0,0};
    float usq = 0.0f;

    const bfu* arow = x + (size_t)(nodeBase + m) * 256 + q * 8;   // A[m][k=8q+32s+j]
#pragma unroll
    for (int s = 0; s < 8; ++s) {
        v8s a = *(const v8s*)(arow + s * 32);
        // B[k][n] = W1[n][k]; lane's B-frag: n = m + 16t, k = 32s + 8q + j
        const bfu* wbase = W1 + (size_t)m * 256 + s * 32 + q * 8;
        v8s w0 = *(const v8s*)(wbase);
        v8s w1 = *(const v8s*)(wbase + 16 * 256);
        v8s w2 = *(const v8s*)(wbase + 32 * 256);
        v8s w3 = *(const v8s*)(wbase + 48 * 256);
#pragma unroll
        for (int j = 0; j < 8; ++j) {
            float av = b2f((bfu)a[j]);
            usq = fmaf(av, av, usq);
        }
        acc0 = __builtin_amdgcn_mfma_f32_16x16x32_bf16(a, w0, acc0, 0, 0, 0);
        acc1 = __builtin_amdgcn_mfma_f32_16x16x32_bf16(a, w1, acc1, 0, 0, 0);
        acc2 = __builtin_amdgcn_mfma_f32_16x16x32_bf16(a, w2, acc2, 0, 0, 0);
        acc3 = __builtin_amdgcn_mfma_f32_16x16x32_bf16(a, w3, acc3, 0, 0, 0);
    }
    // ||u_m||^2: reduce across the 4 quads holding row m
    usq += __shfl_xor(usq, 16, 64);
    usq += __shfl_xor(usq, 32, 64);

    // C layout: row = 4q + r, col = m + 16t
    float P[4], Q[4];
#pragma unroll
    for (int r = 0; r < 4; ++r) {
        float s2 = acc0[r]*acc0[r] + acc1[r]*acc1[r] + acc2[r]*acc2[r] + acc3[r]*acc3[r];
        float sh = acc0[r]*hbv[0] + acc1[r]*hbv[1] + acc2[r]*hbv[2] + acc3[r]*hbv[3];
#pragma unroll
        for (int o = 1; o < 16; o <<= 1) {       // reduce over the 16 col-lanes
            s2 += __shfl_xor(s2, o, 64);
            sh += __shfl_xor(sh, o, 64);
        }
        float usq_r = __shfl(usq, q * 4 + r);    // ||u|| of C-row 4q+r
        float n  = fmaxf(sqrtf(usq_r), EPSV);
        float th = tanhf(n);
        float gamma = th / n;                    // x_hyp = gamma*u (expmap0+proj fold)
        float xn = fmaxf(th, EPSV);
        if (xn > MAXN) { gamma *= MAXN / xn; xn = MAXN; }
        float mxn = fmaxf(gamma * sqrtf(s2), EPSV);
        float rt  = tanhf(mxn / xn * artanh_(xn));
        float k1, x2s, xy;
        if (s2 != 0.0f) {
            k1 = (rt / mxn) * gamma;             // mv = k1 * acc
            float mvn = fmaxf(fabsf(rt), EPSV);
            if (mvn > MAXN) k1 *= MAXN / mvn;    // proj
            float cn = fminf(mvn, MAXN);
            x2s = cn * cn;                       // ||mv||^2 analytic
            xy  = k1 * sh;                       // <mv,hb>
        } else { k1 = 0.0f; x2s = 0.0f; xy = 0.0f; }
        float ca = 1.0f + 2.0f * xy + y2;
        float cb = 1.0f - x2s;
        float den = fmaxf(1.0f + 2.0f * xy + x2s * y2, EPSV);
        float hn2 = ca*ca*x2s + 2.0f*ca*cb*xy + cb*cb*y2;  // ||ca*mv+cb*hb||^2
        float hn = fmaxf(sqrtf(hn2) / den, EPSV);
        float hs = 1.0f;
        if (hn > MAXN) { hs = MAXN / hn; hn = MAXN; }      // proj
        float lam = artanh_(hn) / hn;                      // logmap0
        P[r] = lam * hs * ca * k1 / den;
        Q[r] = lam * hs * cb / den;
    }
#pragma unroll
    for (int r = 0; r < 4; ++r) {
        float* orow = xt + (size_t)(nodeBase + q * 4 + r) * 64 + m;
        orow[ 0] = P[r] * acc0[r] + Q[r] * hbv[0];
        orow[16] = P[r] * acc1[r] + Q[r] * hbv[1];
        orow[32] = P[r] * acc2[r] + Q[r] * hbv[2];
        orow[48] = P[r] * acc3[r] + Q[r] * hbv[3];
    }
}

// ---------- layer 1 fallback (fp32 inputs; round-3 proven) ----------
__global__ __launch_bounds__(256) void hg5_layer1_slow(
    const void* __restrict__ x,
    const void* __restrict__ W1,
    const void* __restrict__ b1v,
    float* __restrict__ xt, const int* __restrict__ flagp, int N)
{
    if (*flagp == 0) return;       // bf16 handled by the MFMA kernel
    const int tid = threadIdx.x, lane = tid & 63, wv = tid >> 6;
    float y2;
    float hb = bias_point(b1v, lane, 1, &y2);
    const int nw = gridDim.x * 4;
    for (int i = blockIdx.x * 4 + wv; i < N; i += nw) {
        float4 p = ((const float4*)((const float*)x + (size_t)i * 256))[lane];
        float u0 = p.x, u1 = p.y, u2 = p.z, u3 = p.w;
        float n = fmaxf(sqrtf(wredsum(u0*u0 + u1*u1 + u2*u2 + u3*u3)), EPSV);
        float th = tanhf(n);
        float gamma = th / n;
        float nh = fmaxf(th, EPSV);
        if (nh > MAXN) { gamma *= MAXN / nh; nh = MAXN; }
        float acc = 0.0f;
        const float4* Wrow = (const float4*)((const float*)W1 + (size_t)lane * 256);
        for (int s = 0; s < 64; ++s) {
            float a0 = __shfl(u0, s), a1 = __shfl(u1, s);
            float a2 = __shfl(u2, s), a3 = __shfl(u3, s);
            float4 w4 = Wrow[s];
            acc = fmaf(a0, w4.x, fmaf(a1, w4.y, fmaf(a2, w4.z, fmaf(a3, w4.w, acc))));
        }
        float o = mobius_tail(gamma * acc, nh, hb, y2);
        xt[(size_t)i * 64 + lane] = o;
    }
}

// ---------- scatter: agg[dst] += w * xt[src] (round-3 proven) ----------
__global__ __launch_bounds__(256) void hg5_scatter(
    const int* __restrict__ src, const int* __restrict__ dst,
    const void* __restrict__ ew,
    const float* __restrict__ xt, float* __restrict__ agg,
    const int* __restrict__ flagp, int E)
{
    const int lane = threadIdx.x & 63;
    const int f = *flagp;
    const long long wid = ((long long)blockIdx.x * blockDim.x + threadIdx.x) >> 6;
    const long long nw = ((long long)gridDim.x * blockDim.x) >> 6;
    for (long long e = wid; e < E; e += nw) {
        int s = src[e], d = dst[e];
        float w = ldx(ew, (size_t)e, f);
        float v = w * xt[(size_t)s * 64 + lane];
        atomicAdd(&agg[(size_t)d * 64 + lane], v);
    }
}

// ---------- layer 2 (round-3 proven) ----------
__global__ __launch_bounds__(256) void hg5_layer2(
    const float* __restrict__ agg,
    const void* __restrict__ W2,
    const void* __restrict__ b2v,
    float* __restrict__ xt2, const int* __restrict__ flagp, int N)
{
    __shared__ bfu wlds[64 * 65];
    __shared__ float xls[4][64];
    const int tid = threadIdx.x, lane = tid & 63, wv = tid >> 6;
    const int f = *flagp;
    if (!f) {
        const bfu* W = (const bfu*)W2;
        for (int idx = tid; idx < 64 * 64; idx += 256) {
            int j = idx >> 6, k = idx & 63;
            wlds[k * 65 + j] = W[idx];
        }
    }
    float y2;
    float hb = bias_point(b2v, lane, f, &y2);
    __syncthreads();
    const int nw = gridDim.x * 4;
    for (int i = blockIdx.x * 4 + wv; i < N; i += nw) {
        float a = agg[(size_t)i * 64 + lane];
        float xn;
        float x2 = agg_transform(a, &xn);
        float acc = 0.0f;
        if (!f) {
            xls[wv][lane] = x2;
            const float* xp = xls[wv];
#pragma unroll
            for (int k = 0; k < 64; k += 4) {
                acc = fmaf(xp[k + 0], b2f(wlds[(k + 0) * 65 + lane]), acc);
                acc = fmaf(xp[k + 1], b2f(wlds[(k + 1) * 65 + lane]), acc);
                acc = fmaf(xp[k + 2], b2f(wlds[(k + 2) * 65 + lane]), acc);
                acc = fmaf(xp[k + 3], b2f(wlds[(k + 3) * 65 + lane]), acc);
            }
        } else {
            const float* Wrow = (const float*)W2 + (size_t)lane * 64;
            for (int s = 0; s < 64; ++s)
                acc = fmaf(__shfl(x2, s), Wrow[s], acc);
        }
        float o = mobius_tail(acc, xn, hb, y2);
        xt2[(size_t)i * 64 + lane] = o;
    }
}

// ---------- final (round-3 proven) ----------
__global__ __launch_bounds__(256) void hg5_final(
    const float* __restrict__ agg, float* __restrict__ out, int N)
{
    const int lane = threadIdx.x & 63, wv = threadIdx.x >> 6;
    const int nw = gridDim.x * 4;
    for (int i = blockIdx.x * 4 + wv; i < N; i += nw) {
        float a = agg[(size_t)i * 64 + lane];
        float xn;
        float o = agg_transform(a, &xn);
        out[(size_t)i * 64 + lane] = o;
    }
}

extern "C" void kernel_launch(void* const* d_in, const int* in_sizes, int n_in,
                              void* d_out, int out_size, void* d_ws, size_t ws_size,
                              hipStream_t stream)
{
    const void* x  = d_in[0];
    const int* src = (const int*)d_in[1];
    const int* dst = (const int*)d_in[2];
    const void* ew = d_in[3];
    const void* W1 = d_in[4];
    const void* b1 = d_in[5];
    const void* W2 = d_in[6];
    const void* b2 = d_in[7];

    const int Dd = in_sizes[5];            // 64
    const int Ff = in_sizes[4] / Dd;       // 256
    const int N  = in_sizes[0] / Ff;       // 80000
    const int E  = in_sizes[1];            // 1280000

    float* out  = (float*)d_out;           // fp32 [N,64]
    float* xt   = (float*)d_out;           // tangent-vector scratch shares d_out
    float* agg  = (float*)d_ws;            // fp32 [N,64] accumulator
    int*   flag = (int*)(agg + (size_t)N * Dd);

    const int n4 = (N * Dd) / 4;
    const int blkL1 = (N + 63) / 64;       // MFMA: wave per 16 nodes, 4 waves/block

    hg5_probe      <<<1,     64,  0, stream>>>(b1, flag);
    hg5_layer1_mfma<<<blkL1, 256, 0, stream>>>((const bfu*)x, (const bfu*)W1,
                                               (const bfu*)b1, xt, flag, N);
    hg5_layer1_slow<<<2048,  256, 0, stream>>>(x, W1, b1, xt, flag, N);
    hg5_zero       <<<1024,  256, 0, stream>>>(agg, n4);
    hg5_scatter    <<<16384, 256, 0, stream>>>(src, dst, ew, xt, agg, flag, E);
    hg5_layer2     <<<2048,  256, 0, stream>>>(agg, W2, b2, xt, flag, N);   // in-place
    hg5_zero       <<<1024,  256, 0, stream>>>(agg, n4);
    hg5_scatter    <<<16384, 256, 0, stream>>>(src, dst, ew, xt, agg, flag, E);
    hg5_final      <<<2048,  256, 0, stream>>>(agg, out, N);                // last
}

// Round 6
// 893.996 us; speedup vs baseline: 1.5882x; 1.5882x over previous
//
#include <hip/hip_runtime.h>

// HGCN forward (2-layer hyperbolic GCN), Poincare ball c=1.
// ROUND-5 FINDING: all float inputs are fp32 (bf16-rounded values stored as
// fp32) -- the fp32 fallback path is what passed rounds 3/5. Output fp32.
// Round 6 = hard-code fp32 + enable MFMA layer1 (fp32 loads -> bf16 frags).
// Scatter/layer2/final are the round-5 fp32 paths, unchanged structurally.

#define EPSV 1e-15f
#define MAXN 0.996f   // (1 - 4e-3) / sqrt(c), c = 1

typedef unsigned short bfu;
typedef __attribute__((ext_vector_type(8))) short v8s;   // 8 bf16 (4 VGPRs)
typedef __attribute__((ext_vector_type(4))) float v4f;   // MFMA acc

__device__ __forceinline__ bfu f2b(float f) {   // fp32 -> bf16, RNE
    unsigned int u;
    __builtin_memcpy(&u, &f, sizeof(u));
    u += 0x7fffu + ((u >> 16) & 1u);
    return (bfu)(u >> 16);
}

__device__ __forceinline__ v8s cvt8(const float* f) {
    v8s r;
#pragma unroll
    for (int j = 0; j < 8; ++j) r[j] = (short)f2b(f[j]);
    return r;
}

__device__ __forceinline__ float wredsum(float v) {
#pragma unroll
    for (int o = 32; o > 0; o >>= 1) v += __shfl_xor(v, o, 64);
    return v;  // butterfly: bit-identical across all 64 lanes
}

__device__ __forceinline__ float artanh_(float x) {
    x = fminf(fmaxf(x, -1.0f + 1e-7f), 1.0f - 1e-7f);
    return 0.5f * logf((1.0f + x) / (1.0f - x));
}

// ===== wave-per-node helpers (proven rounds 3/5, fp32) =====

__device__ __forceinline__ float mobius_tail(float mx, float xn, float hb, float y2) {
    float mxn2 = wredsum(mx * mx);
    unsigned long long nz = __ballot(mx != 0.0f);
    float mxn = fmaxf(sqrtf(mxn2), EPSV);
    float rt = tanhf(mxn / xn * artanh_(xn));
    float mv, x2s;
    if (nz != 0ull) {
        mv = (rt / mxn) * mx;
        float mvn = fmaxf(fabsf(rt), EPSV);
        if (mvn > MAXN) mv *= MAXN / mvn;
        float cn = fminf(mvn, MAXN);
        x2s = cn * cn;
    } else { mv = 0.0f; x2s = 0.0f; }
    float xy = wredsum(mv * hb);
    float ca = 1.0f + 2.0f * xy + y2;
    float cb = 1.0f - x2s;
    float den = fmaxf(1.0f + 2.0f * xy + x2s * y2, EPSV);
    float hj = (ca * mv + cb * hb) / den;
    float hn = fmaxf(sqrtf(wredsum(hj * hj)), EPSV);
    if (hn > MAXN) { hj *= MAXN / hn; hn = MAXN; }
    return (artanh_(hn) / hn) * hj;
}

__device__ __forceinline__ float agg_transform(float a, float* xn_out) {
    float n = fmaxf(sqrtf(wredsum(a * a)), EPSV);
    float th = tanhf(n);
    float g = th / n;
    float nh = fmaxf(th, EPSV);
    if (nh > MAXN) { g *= MAXN / nh; nh = MAXN; }
    float h = g * a;
    float t = fmaxf((artanh_(nh) / nh) * h, 0.0f);
    float n2 = fmaxf(sqrtf(wredsum(t * t)), EPSV);
    float th2 = tanhf(n2);
    float g2 = th2 / n2;
    float nh2 = fmaxf(th2, EPSV);
    if (nh2 > MAXN) { g2 *= MAXN / nh2; nh2 = MAXN; }
    *xn_out = nh2;
    return g2 * t;
}

__device__ __forceinline__ float bias_point(const float* bv, int lane, float* y2) {
    float b = bv[lane];
    float bn = fmaxf(sqrtf(wredsum(b * b)), EPSV);
    float gs = tanhf(bn) / bn;
    float hbn = fmaxf(tanhf(bn), EPSV);
    if (hbn > MAXN) gs *= MAXN / hbn;
    float hb = gs * b;
    *y2 = wredsum(hb * hb);
    return hb;
}

__global__ __launch_bounds__(256) void hg6_zero(float* __restrict__ p, int n4) {
    const float4 z = make_float4(0.f, 0.f, 0.f, 0.f);
    int stride = gridDim.x * blockDim.x;
    for (int i = blockIdx.x * blockDim.x + threadIdx.x; i < n4; i += stride)
        ((float4*)p)[i] = z;
}

// ===== layer 1: MFMA GEMM (fp32 in, bf16 frags), wave per 16 nodes =====
__global__ __launch_bounds__(256) void hg6_layer1(
    const float* __restrict__ x,     // [N,256] fp32 (bf16-grid values)
    const float* __restrict__ W1,    // [64,256] fp32 row-major
    const float* __restrict__ b1v,   // [64] fp32
    float* __restrict__ xt, int N)
{
    const int tid = threadIdx.x, lane = tid & 63, wv = tid >> 6;
    const int nodeBase = (blockIdx.x * 4 + wv) * 16;
    if (nodeBase >= N) return;

    float y2;
    float hb = bias_point(b1v, lane, &y2);         // lane = dim layout
    float hbv[4];
#pragma unroll
    for (int t = 0; t < 4; ++t) hbv[t] = __shfl(hb, (lane & 15) + 16 * t);

    const int m = lane & 15, q = lane >> 4;
    v4f acc0 = {0,0,0,0}, acc1 = {0,0,0,0}, acc2 = {0,0,0,0}, acc3 = {0,0,0,0};
    float usq = 0.0f;

    const float* arow = x + (size_t)(nodeBase + m) * 256 + q * 8;  // A[m][k=8q+32s+j]
#pragma unroll
    for (int s = 0; s < 8; ++s) {
        float af[8];
        *(float4*)(af)     = *(const float4*)(arow + s * 32);
        *(float4*)(af + 4) = *(const float4*)(arow + s * 32 + 4);
#pragma unroll
        for (int j = 0; j < 8; ++j) usq = fmaf(af[j], af[j], usq);
        v8s a = cvt8(af);
        // B[k][n] = W1[n][k]; lane's frag for tile t: n = m+16t, k = 32s+8q+j
        const float* wbase = W1 + (size_t)m * 256 + s * 32 + q * 8;
        float wf[8];
        *(float4*)(wf) = *(const float4*)(wbase);
        *(float4*)(wf + 4) = *(const float4*)(wbase + 4);
        acc0 = __builtin_amdgcn_mfma_f32_16x16x32_bf16(a, cvt8(wf), acc0, 0, 0, 0);
        *(float4*)(wf) = *(const float4*)(wbase + 16 * 256);
        *(float4*)(wf + 4) = *(const float4*)(wbase + 16 * 256 + 4);
        acc1 = __builtin_amdgcn_mfma_f32_16x16x32_bf16(a, cvt8(wf), acc1, 0, 0, 0);
        *(float4*)(wf) = *(const float4*)(wbase + 32 * 256);
        *(float4*)(wf + 4) = *(const float4*)(wbase + 32 * 256 + 4);
        acc2 = __builtin_amdgcn_mfma_f32_16x16x32_bf16(a, cvt8(wf), acc2, 0, 0, 0);
        *(float4*)(wf) = *(const float4*)(wbase + 48 * 256);
        *(float4*)(wf + 4) = *(const float4*)(wbase + 48 * 256 + 4);
        acc3 = __builtin_amdgcn_mfma_f32_16x16x32_bf16(a, cvt8(wf), acc3, 0, 0, 0);
    }
    // ||u_m||^2: reduce across the 4 q-groups holding row m
    usq += __shfl_xor(usq, 16, 64);
    usq += __shfl_xor(usq, 32, 64);

    // C layout: row = 4q + r, col = m + 16t  [m89/m91-verified]
    float P[4], Q[4];
#pragma unroll
    for (int r = 0; r < 4; ++r) {
        float s2 = acc0[r]*acc0[r] + acc1[r]*acc1[r] + acc2[r]*acc2[r] + acc3[r]*acc3[r];
        float sh = acc0[r]*hbv[0] + acc1[r]*hbv[1] + acc2[r]*hbv[2] + acc3[r]*hbv[3];
#pragma unroll
        for (int o = 1; o < 16; o <<= 1) {       // reduce over the 16 col-lanes
            s2 += __shfl_xor(s2, o, 64);
            sh += __shfl_xor(sh, o, 64);
        }
        float usq_r = __shfl(usq, q * 4 + r);    // ||u||^2 of C-row 4q+r
        float n  = fmaxf(sqrtf(usq_r), EPSV);
        float th = tanhf(n);
        float gamma = th / n;                    // expmap0+proj fold: x_hyp = gamma*u
        float xn = fmaxf(th, EPSV);
        if (xn > MAXN) { gamma *= MAXN / xn; xn = MAXN; }
        float mxn = fmaxf(gamma * sqrtf(s2), EPSV);
        float rt  = tanhf(mxn / xn * artanh_(xn));
        float k1, x2s, xy;
        if (s2 != 0.0f) {
            k1 = (rt / mxn) * gamma;             // mv = k1 * acc
            float mvn = fmaxf(fabsf(rt), EPSV);
            if (mvn > MAXN) k1 *= MAXN / mvn;    // proj
            float cn = fminf(mvn, MAXN);
            x2s = cn * cn;                       // ||mv||^2 analytic
            xy  = k1 * sh;                       // <mv,hb>
        } else { k1 = 0.0f; x2s = 0.0f; xy = 0.0f; }
        float ca = 1.0f + 2.0f * xy + y2;
        float cb = 1.0f - x2s;
        float den = fmaxf(1.0f + 2.0f * xy + x2s * y2, EPSV);
        float hn2 = ca*ca*x2s + 2.0f*ca*cb*xy + cb*cb*y2;  // ||ca*mv+cb*hb||^2
        float hn = fmaxf(sqrtf(hn2) / den, EPSV);
        float hs = 1.0f;
        if (hn > MAXN) { hs = MAXN / hn; hn = MAXN; }      // proj
        float lam = artanh_(hn) / hn;                      // logmap0
        P[r] = lam * hs * ca * k1 / den;
        Q[r] = lam * hs * cb / den;
    }
#pragma unroll
    for (int r = 0; r < 4; ++r) {
        float* orow = xt + (size_t)(nodeBase + q * 4 + r) * 64 + m;
        orow[ 0] = P[r] * acc0[r] + Q[r] * hbv[0];
        orow[16] = P[r] * acc1[r] + Q[r] * hbv[1];
        orow[32] = P[r] * acc2[r] + Q[r] * hbv[2];
        orow[48] = P[r] * acc3[r] + Q[r] * hbv[3];
    }
}

// ===== scatter: agg[dst] += w * xt[src] (round-5 proven, fp32) =====
__global__ __launch_bounds__(256) void hg6_scatter(
    const int* __restrict__ src, const int* __restrict__ dst,
    const float* __restrict__ ew,
    const float* __restrict__ xt, float* __restrict__ agg, int E)
{
    const int lane = threadIdx.x & 63;
    const long long wid = ((long long)blockIdx.x * blockDim.x + threadIdx.x) >> 6;
    const long long nw = ((long long)gridDim.x * blockDim.x) >> 6;
    for (long long e = wid; e < E; e += nw) {
        int s = src[e], d = dst[e];
        float w = ew[e];
        float v = w * xt[(size_t)s * 64 + lane];
        atomicAdd(&agg[(size_t)d * 64 + lane], v);
    }
}

// ===== layer 2 (round-5 proven fp32 path) =====
__global__ __launch_bounds__(256) void hg6_layer2(
    const float* __restrict__ agg,
    const float* __restrict__ W2,    // [64,64] fp32
    const float* __restrict__ b2v,   // [64] fp32
    float* __restrict__ xt2, int N)
{
    const int lane = threadIdx.x & 63, wv = threadIdx.x >> 6;
    float y2;
    float hb = bias_point(b2v, lane, &y2);
    const int nw = gridDim.x * 4;
    for (int i = blockIdx.x * 4 + wv; i < N; i += nw) {
        float a = agg[(size_t)i * 64 + lane];
        float xn;
        float x2 = agg_transform(a, &xn);
        float acc = 0.0f;
        const float* Wrow = W2 + (size_t)lane * 64;
        for (int s = 0; s < 64; ++s)
            acc = fmaf(__shfl(x2, s), Wrow[s], acc);
        float o = mobius_tail(acc, xn, hb, y2);
        xt2[(size_t)i * 64 + lane] = o;
    }
}

// ===== final (round-5 proven) =====
__global__ __launch_bounds__(256) void hg6_final(
    const float* __restrict__ agg, float* __restrict__ out, int N)
{
    const int lane = threadIdx.x & 63, wv = threadIdx.x >> 6;
    const int nw = gridDim.x * 4;
    for (int i = blockIdx.x * 4 + wv; i < N; i += nw) {
        float a = agg[(size_t)i * 64 + lane];
        float xn;
        float o = agg_transform(a, &xn);
        out[(size_t)i * 64 + lane] = o;
    }
}

extern "C" void kernel_launch(void* const* d_in, const int* in_sizes, int n_in,
                              void* d_out, int out_size, void* d_ws, size_t ws_size,
                              hipStream_t stream)
{
    const float* x  = (const float*)d_in[0];
    const int* src  = (const int*)d_in[1];
    const int* dst  = (const int*)d_in[2];
    const float* ew = (const float*)d_in[3];
    const float* W1 = (const float*)d_in[4];
    const float* b1 = (const float*)d_in[5];
    const float* W2 = (const float*)d_in[6];
    const float* b2 = (const float*)d_in[7];

    const int Dd = in_sizes[5];            // 64
    const int Ff = in_sizes[4] / Dd;       // 256
    const int N  = in_sizes[0] / Ff;       // 80000
    const int E  = in_sizes[1];            // 1280000

    float* out  = (float*)d_out;           // fp32 [N,64]
    float* xt   = (float*)d_out;           // tangent-vector scratch shares d_out
    float* agg  = (float*)d_ws;            // fp32 [N,64] accumulator

    const int n4 = (N * Dd) / 4;
    const int blkL1 = (N + 63) / 64;       // wave per 16 nodes, 4 waves/block

    hg6_layer1 <<<blkL1, 256, 0, stream>>>(x, W1, b1, xt, N);
    hg6_zero   <<<1024,  256, 0, stream>>>(agg, n4);
    hg6_scatter<<<16384, 256, 0, stream>>>(src, dst, ew, xt, agg, E);
    hg6_layer2 <<<2048,  256, 0, stream>>>(agg, W2, b2, xt, N);   // in-place on d_out
    hg6_zero   <<<1024,  256, 0, stream>>>(agg, n4);
    hg6_scatter<<<16384, 256, 0, stream>>>(src, dst, ew, xt, agg, E);
    hg6_final  <<<2048,  256, 0, stream>>>(agg, out, N);          // overwrites d_out last
}

// Round 7
// 727.898 us; speedup vs baseline: 1.9506x; 1.2282x over previous
//
#include <hip/hip_runtime.h>

// HGCN forward (2-layer hyperbolic GCN), Poincare ball c=1. fp32 in/out
// (values bf16-grid). Round 7 = round 6 with the atomic scatter replaced by
// CSR build (count/scan/fill) + atomic-free gather, branch on ws_size with
// the proven zero+scatter fallback. layer1 (MFMA) / layer2 / final unchanged.

#define EPSV 1e-15f
#define MAXN 0.996f   // (1 - 4e-3) / sqrt(c), c = 1

typedef unsigned short bfu;
typedef __attribute__((ext_vector_type(8))) short v8s;   // 8 bf16 (4 VGPRs)
typedef __attribute__((ext_vector_type(4))) float v4f;   // MFMA acc

__device__ __forceinline__ bfu f2b(float f) {   // fp32 -> bf16, RNE
    unsigned int u;
    __builtin_memcpy(&u, &f, sizeof(u));
    u += 0x7fffu + ((u >> 16) & 1u);
    return (bfu)(u >> 16);
}

__device__ __forceinline__ v8s cvt8(const float* f) {
    v8s r;
#pragma unroll
    for (int j = 0; j < 8; ++j) r[j] = (short)f2b(f[j]);
    return r;
}

__device__ __forceinline__ float wredsum(float v) {
#pragma unroll
    for (int o = 32; o > 0; o >>= 1) v += __shfl_xor(v, o, 64);
    return v;
}

__device__ __forceinline__ float artanh_(float x) {
    x = fminf(fmaxf(x, -1.0f + 1e-7f), 1.0f - 1e-7f);
    return 0.5f * logf((1.0f + x) / (1.0f - x));
}

__device__ __forceinline__ float mobius_tail(float mx, float xn, float hb, float y2) {
    float mxn2 = wredsum(mx * mx);
    unsigned long long nz = __ballot(mx != 0.0f);
    float mxn = fmaxf(sqrtf(mxn2), EPSV);
    float rt = tanhf(mxn / xn * artanh_(xn));
    float mv, x2s;
    if (nz != 0ull) {
        mv = (rt / mxn) * mx;
        float mvn = fmaxf(fabsf(rt), EPSV);
        if (mvn > MAXN) mv *= MAXN / mvn;
        float cn = fminf(mvn, MAXN);
        x2s = cn * cn;
    } else { mv = 0.0f; x2s = 0.0f; }
    float xy = wredsum(mv * hb);
    float ca = 1.0f + 2.0f * xy + y2;
    float cb = 1.0f - x2s;
    float den = fmaxf(1.0f + 2.0f * xy + x2s * y2, EPSV);
    float hj = (ca * mv + cb * hb) / den;
    float hn = fmaxf(sqrtf(wredsum(hj * hj)), EPSV);
    if (hn > MAXN) { hj *= MAXN / hn; hn = MAXN; }
    return (artanh_(hn) / hn) * hj;
}

__device__ __forceinline__ float agg_transform(float a, float* xn_out) {
    float n = fmaxf(sqrtf(wredsum(a * a)), EPSV);
    float th = tanhf(n);
    float g = th / n;
    float nh = fmaxf(th, EPSV);
    if (nh > MAXN) { g *= MAXN / nh; nh = MAXN; }
    float h = g * a;
    float t = fmaxf((artanh_(nh) / nh) * h, 0.0f);
    float n2 = fmaxf(sqrtf(wredsum(t * t)), EPSV);
    float th2 = tanhf(n2);
    float g2 = th2 / n2;
    float nh2 = fmaxf(th2, EPSV);
    if (nh2 > MAXN) { g2 *= MAXN / nh2; nh2 = MAXN; }
    *xn_out = nh2;
    return g2 * t;
}

__device__ __forceinline__ float bias_point(const float* bv, int lane, float* y2) {
    float b = bv[lane];
    float bn = fmaxf(sqrtf(wredsum(b * b)), EPSV);
    float gs = tanhf(bn) / bn;
    float hbn = fmaxf(tanhf(bn), EPSV);
    if (hbn > MAXN) gs *= MAXN / hbn;
    float hb = gs * b;
    *y2 = wredsum(hb * hb);
    return hb;
}

__global__ __launch_bounds__(256) void hg7_zero(float* __restrict__ p, int n4) {
    const float4 z = make_float4(0.f, 0.f, 0.f, 0.f);
    int stride = gridDim.x * blockDim.x;
    for (int i = blockIdx.x * blockDim.x + threadIdx.x; i < n4; i += stride)
        ((float4*)p)[i] = z;
}

// ===== layer 1: MFMA GEMM (round-6 proven) =====
__global__ __launch_bounds__(256) void hg7_layer1(
    const float* __restrict__ x,     // [N,256]
    const float* __restrict__ W1,    // [64,256] row-major
    const float* __restrict__ b1v,   // [64]
    float* __restrict__ xt, int N)
{
    const int tid = threadIdx.x, lane = tid & 63, wv = tid >> 6;
    const int nodeBase = (blockIdx.x * 4 + wv) * 16;
    if (nodeBase >= N) return;

    float y2;
    float hb = bias_point(b1v, lane, &y2);
    float hbv[4];
#pragma unroll
    for (int t = 0; t < 4; ++t) hbv[t] = __shfl(hb, (lane & 15) + 16 * t);

    const int m = lane & 15, q = lane >> 4;
    v4f acc0 = {0,0,0,0}, acc1 = {0,0,0,0}, acc2 = {0,0,0,0}, acc3 = {0,0,0,0};
    float usq = 0.0f;

    const float* arow = x + (size_t)(nodeBase + m) * 256 + q * 8;
#pragma unroll
    for (int s = 0; s < 8; ++s) {
        float af[8];
        *(float4*)(af)     = *(const float4*)(arow + s * 32);
        *(float4*)(af + 4) = *(const float4*)(arow + s * 32 + 4);
#pragma unroll
        for (int j = 0; j < 8; ++j) usq = fmaf(af[j], af[j], usq);
        v8s a = cvt8(af);
        const float* wbase = W1 + (size_t)m * 256 + s * 32 + q * 8;
        float wf[8];
        *(float4*)(wf) = *(const float4*)(wbase);
        *(float4*)(wf + 4) = *(const float4*)(wbase + 4);
        acc0 = __builtin_amdgcn_mfma_f32_16x16x32_bf16(a, cvt8(wf), acc0, 0, 0, 0);
        *(float4*)(wf) = *(const float4*)(wbase + 16 * 256);
        *(float4*)(wf + 4) = *(const float4*)(wbase + 16 * 256 + 4);
        acc1 = __builtin_amdgcn_mfma_f32_16x16x32_bf16(a, cvt8(wf), acc1, 0, 0, 0);
        *(float4*)(wf) = *(const float4*)(wbase + 32 * 256);
        *(float4*)(wf + 4) = *(const float4*)(wbase + 32 * 256 + 4);
        acc2 = __builtin_amdgcn_mfma_f32_16x16x32_bf16(a, cvt8(wf), acc2, 0, 0, 0);
        *(float4*)(wf) = *(const float4*)(wbase + 48 * 256);
        *(float4*)(wf + 4) = *(const float4*)(wbase + 48 * 256 + 4);
        acc3 = __builtin_amdgcn_mfma_f32_16x16x32_bf16(a, cvt8(wf), acc3, 0, 0, 0);
    }
    usq += __shfl_xor(usq, 16, 64);
    usq += __shfl_xor(usq, 32, 64);

    float P[4], Q[4];
#pragma unroll
    for (int r = 0; r < 4; ++r) {
        float s2 = acc0[r]*acc0[r] + acc1[r]*acc1[r] + acc2[r]*acc2[r] + acc3[r]*acc3[r];
        float sh = acc0[r]*hbv[0] + acc1[r]*hbv[1] + acc2[r]*hbv[2] + acc3[r]*hbv[3];
#pragma unroll
        for (int o = 1; o < 16; o <<= 1) {
            s2 += __shfl_xor(s2, o, 64);
            sh += __shfl_xor(sh, o, 64);
        }
        float usq_r = __shfl(usq, q * 4 + r);
        float n  = fmaxf(sqrtf(usq_r), EPSV);
        float th = tanhf(n);
        float gamma = th / n;
        float xn = fmaxf(th, EPSV);
        if (xn > MAXN) { gamma *= MAXN / xn; xn = MAXN; }
        float mxn = fmaxf(gamma * sqrtf(s2), EPSV);
        float rt  = tanhf(mxn / xn * artanh_(xn));
        float k1, x2s, xy;
        if (s2 != 0.0f) {
            k1 = (rt / mxn) * gamma;
            float mvn = fmaxf(fabsf(rt), EPSV);
            if (mvn > MAXN) k1 *= MAXN / mvn;
            float cn = fminf(mvn, MAXN);
            x2s = cn * cn;
            xy  = k1 * sh;
        } else { k1 = 0.0f; x2s = 0.0f; xy = 0.0f; }
        float ca = 1.0f + 2.0f * xy + y2;
        float cb = 1.0f - x2s;
        float den = fmaxf(1.0f + 2.0f * xy + x2s * y2, EPSV);
        float hn2 = ca*ca*x2s + 2.0f*ca*cb*xy + cb*cb*y2;
        float hn = fmaxf(sqrtf(hn2) / den, EPSV);
        float hs = 1.0f;
        if (hn > MAXN) { hs = MAXN / hn; hn = MAXN; }
        float lam = artanh_(hn) / hn;
        P[r] = lam * hs * ca * k1 / den;
        Q[r] = lam * hs * cb / den;
    }
#pragma unroll
    for (int r = 0; r < 4; ++r) {
        float* orow = xt + (size_t)(nodeBase + q * 4 + r) * 64 + m;
        orow[ 0] = P[r] * acc0[r] + Q[r] * hbv[0];
        orow[16] = P[r] * acc1[r] + Q[r] * hbv[1];
        orow[32] = P[r] * acc2[r] + Q[r] * hbv[2];
        orow[48] = P[r] * acc3[r] + Q[r] * hbv[3];
    }
}

// ===== CSR build =====
__global__ __launch_bounds__(256) void hg7_zero_i32(int* __restrict__ p, int n) {
    int stride = gridDim.x * blockDim.x;
    for (int i = blockIdx.x * blockDim.x + threadIdx.x; i < n; i += stride) p[i] = 0;
}

__global__ __launch_bounds__(256) void hg7_count(
    const int* __restrict__ dst, int* __restrict__ deg, int E) {
    int stride = gridDim.x * blockDim.x;
    for (int e = blockIdx.x * blockDim.x + threadIdx.x; e < E; e += stride)
        atomicAdd(&deg[dst[e]], 1);
}

// single-block exclusive scan: deg[0..N) -> row_start[0..N], copy to cursor
__global__ __launch_bounds__(1024) void hg7_scan(
    const int* __restrict__ deg, int* __restrict__ row_start,
    int* __restrict__ cursor, int N) {
    __shared__ int wsum[16];
    __shared__ int srun;
    const int tid = threadIdx.x, lane = tid & 63, wv = tid >> 6;
    if (tid == 0) srun = 0;
    __syncthreads();
    for (int base = 0; base < N; base += 1024) {
        int i = base + tid;
        int v = (i < N) ? deg[i] : 0;
        int incl = v;
#pragma unroll
        for (int o = 1; o < 64; o <<= 1) {
            int nbr = __shfl_up(incl, o, 64);
            if (lane >= o) incl += nbr;
        }
        if (lane == 63) wsum[wv] = incl;
        __syncthreads();
        int add = 0;
#pragma unroll
        for (int w = 0; w < 16; ++w) { int s = wsum[w]; if (w < wv) add += s; }
        int excl = srun + add + incl - v;
        if (i < N) { row_start[i] = excl; cursor[i] = excl; }
        __syncthreads();
        if (tid == 1023) srun += add + incl;   // block total
        __syncthreads();
    }
    if (tid == 0) row_start[N] = srun;
}

__global__ __launch_bounds__(256) void hg7_fill(
    const int* __restrict__ src, const int* __restrict__ dst,
    const float* __restrict__ ew, int* __restrict__ cursor,
    int* __restrict__ csr_src, float* __restrict__ csr_w, int E) {
    int stride = gridDim.x * blockDim.x;
    for (int e = blockIdx.x * blockDim.x + threadIdx.x; e < E; e += stride) {
        int d = dst[e];
        int slot = atomicAdd(&cursor[d], 1);
        csr_src[slot] = src[e];
        csr_w[slot]   = ew[e];
    }
}

// ===== gather: agg[d] = sum_e w_e * xt[src_e]; wave per dst, no atomics =====
__global__ __launch_bounds__(256) void hg7_gather(
    const int* __restrict__ row_start, const int* __restrict__ csr_src,
    const float* __restrict__ csr_w, const float* __restrict__ xt,
    float* __restrict__ agg, int N) {
    const int lane = threadIdx.x & 63, wv = threadIdx.x >> 6;
    const int d = blockIdx.x * 4 + wv;
    if (d >= N) return;
    const int n0 = row_start[d], n1 = row_start[d + 1];
    float acc = 0.0f;
    for (int base = n0; base < n1; base += 64) {
        int cnt = n1 - base; if (cnt > 64) cnt = 64;
        int   sL = 0; float wL = 0.0f;
        if (lane < cnt) { sL = csr_src[base + lane]; wL = csr_w[base + lane]; }
        for (int j = 0; j < cnt; ++j) {
            int s = __shfl(sL, j);
            float w = __shfl(wL, j);
            acc = fmaf(w, xt[(size_t)s * 64 + lane], acc);
        }
    }
    agg[(size_t)d * 64 + lane] = acc;
}

// ===== atomic scatter fallback (round-6 proven) =====
__global__ __launch_bounds__(256) void hg7_scatter(
    const int* __restrict__ src, const int* __restrict__ dst,
    const float* __restrict__ ew,
    const float* __restrict__ xt, float* __restrict__ agg, int E)
{
    const int lane = threadIdx.x & 63;
    const long long wid = ((long long)blockIdx.x * blockDim.x + threadIdx.x) >> 6;
    const long long nw = ((long long)gridDim.x * blockDim.x) >> 6;
    for (long long e = wid; e < E; e += nw) {
        int s = src[e], d = dst[e];
        atomicAdd(&agg[(size_t)d * 64 + lane], ew[e] * xt[(size_t)s * 64 + lane]);
    }
}

// ===== layer 2 (round-6 proven) =====
__global__ __launch_bounds__(256) void hg7_layer2(
    const float* __restrict__ agg,
    const float* __restrict__ W2,    // [64,64]
    const float* __restrict__ b2v,   // [64]
    float* __restrict__ xt2, int N)
{
    const int lane = threadIdx.x & 63, wv = threadIdx.x >> 6;
    float y2;
    float hb = bias_point(b2v, lane, &y2);
    const int nw = gridDim.x * 4;
    for (int i = blockIdx.x * 4 + wv; i < N; i += nw) {
        float a = agg[(size_t)i * 64 + lane];
        float xn;
        float x2 = agg_transform(a, &xn);
        float acc = 0.0f;
        const float* Wrow = W2 + (size_t)lane * 64;
        for (int s = 0; s < 64; ++s)
            acc = fmaf(__shfl(x2, s), Wrow[s], acc);
        float o = mobius_tail(acc, xn, hb, y2);
        xt2[(size_t)i * 64 + lane] = o;
    }
}

// ===== final (round-6 proven) =====
__global__ __launch_bounds__(256) void hg7_final(
    const float* __restrict__ agg, float* __restrict__ out, int N)
{
    const int lane = threadIdx.x & 63, wv = threadIdx.x >> 6;
    const int nw = gridDim.x * 4;
    for (int i = blockIdx.x * 4 + wv; i < N; i += nw) {
        float a = agg[(size_t)i * 64 + lane];
        float xn;
        float o = agg_transform(a, &xn);
        out[(size_t)i * 64 + lane] = o;
    }
}

extern "C" void kernel_launch(void* const* d_in, const int* in_sizes, int n_in,
                              void* d_out, int out_size, void* d_ws, size_t ws_size,
                              hipStream_t stream)
{
    const float* x  = (const float*)d_in[0];
    const int* src  = (const int*)d_in[1];
    const int* dst  = (const int*)d_in[2];
    const float* ew = (const float*)d_in[3];
    const float* W1 = (const float*)d_in[4];
    const float* b1 = (const float*)d_in[5];
    const float* W2 = (const float*)d_in[6];
    const float* b2 = (const float*)d_in[7];

    const int Dd = in_sizes[5];            // 64
    const int Ff = in_sizes[4] / Dd;       // 256
    const int N  = in_sizes[0] / Ff;       // 80000
    const int E  = in_sizes[1];            // 1280000

    float* out  = (float*)d_out;
    float* xt   = (float*)d_out;           // [N,64] tangent scratch in d_out

    // d_ws layout: [agg f32 N*64][deg N][row_start N+1][cursor N][csr_src E][csr_w E]
    float* agg     = (float*)d_ws;
    int*   deg     = (int*)(agg + (size_t)N * Dd);
    int*   rowst   = deg + N;
    int*   cursor  = rowst + (N + 1);
    int*   csr_src = cursor + N;
    float* csr_w   = (float*)(csr_src + E);
    const size_t ws_need = (size_t)N * Dd * 4 + (size_t)(3 * N + 1) * 4 + (size_t)E * 8;
    const bool use_csr = ws_size >= ws_need;

    const int blkL1 = (N + 63) / 64;       // wave per 16 nodes
    const int blkG  = (N + 3) / 4;         // wave per dst node
    const int n4    = (N * Dd) / 4;

    hg7_layer1<<<blkL1, 256, 0, stream>>>(x, W1, b1, xt, N);
    if (use_csr) {
        hg7_zero_i32<<<128,  256, 0, stream>>>(deg, N);
        hg7_count   <<<2048, 256, 0, stream>>>(dst, deg, E);
        hg7_scan    <<<1,   1024, 0, stream>>>(deg, rowst, cursor, N);
        hg7_fill    <<<2048, 256, 0, stream>>>(src, dst, ew, cursor, csr_src, csr_w, E);
        hg7_gather  <<<blkG, 256, 0, stream>>>(rowst, csr_src, csr_w, xt, agg, N);
        hg7_layer2  <<<2048, 256, 0, stream>>>(agg, W2, b2, xt, N);
        hg7_gather  <<<blkG, 256, 0, stream>>>(rowst, csr_src, csr_w, xt, agg, N);
    } else {
        hg7_zero   <<<1024,  256, 0, stream>>>(agg, n4);
        hg7_scatter<<<16384, 256, 0, stream>>>(src, dst, ew, xt, agg, E);
        hg7_layer2 <<<2048,  256, 0, stream>>>(agg, W2, b2, xt, N);
        hg7_zero   <<<1024,  256, 0, stream>>>(agg, n4);
        hg7_scatter<<<16384, 256, 0, stream>>>(src, dst, ew, xt, agg, E);
    }
    hg7_final<<<2048, 256, 0, stream>>>(agg, out, N);   // overwrites d_out last
}

// Round 8
// 581.355 us; speedup vs baseline: 2.4423x; 1.2521x over previous
//
#include <hip/hip_runtime.h>

// HGCN forward (2-layer hyperbolic GCN), Poincare ball c=1. fp32 in/out
// (values bf16-grid). Round 8 (CSR branch): layer2 -> MFMA (fused HypAct +
// matvec + mobius tail, in-place on agg); final fused into gather #2.
// layer1 / CSR build / gather #1 unchanged (round-7 proven). Non-CSR
// fallback = round-7 path verbatim.

#define EPSV 1e-15f
#define MAXN 0.996f   // (1 - 4e-3) / sqrt(c), c = 1

typedef unsigned short bfu;
typedef __attribute__((ext_vector_type(8))) short v8s;   // 8 bf16 (4 VGPRs)
typedef __attribute__((ext_vector_type(4))) float v4f;   // MFMA acc

__device__ __forceinline__ bfu f2b(float f) {   // fp32 -> bf16, RNE
    unsigned int u;
    __builtin_memcpy(&u, &f, sizeof(u));
    u += 0x7fffu + ((u >> 16) & 1u);
    return (bfu)(u >> 16);
}

__device__ __forceinline__ v8s cvt8(const float* f) {
    v8s r;
#pragma unroll
    for (int j = 0; j < 8; ++j) r[j] = (short)f2b(f[j]);
    return r;
}

__device__ __forceinline__ float wredsum(float v) {
#pragma unroll
    for (int o = 32; o > 0; o >>= 1) v += __shfl_xor(v, o, 64);
    return v;
}

__device__ __forceinline__ float artanh_(float x) {
    x = fminf(fmaxf(x, -1.0f + 1e-7f), 1.0f - 1e-7f);
    return 0.5f * logf((1.0f + x) / (1.0f - x));
}

__device__ __forceinline__ float mobius_tail(float mx, float xn, float hb, float y2) {
    float mxn2 = wredsum(mx * mx);
    unsigned long long nz = __ballot(mx != 0.0f);
    float mxn = fmaxf(sqrtf(mxn2), EPSV);
    float rt = tanhf(mxn / xn * artanh_(xn));
    float mv, x2s;
    if (nz != 0ull) {
        mv = (rt / mxn) * mx;
        float mvn = fmaxf(fabsf(rt), EPSV);
        if (mvn > MAXN) mv *= MAXN / mvn;
        float cn = fminf(mvn, MAXN);
        x2s = cn * cn;
    } else { mv = 0.0f; x2s = 0.0f; }
    float xy = wredsum(mv * hb);
    float ca = 1.0f + 2.0f * xy + y2;
    float cb = 1.0f - x2s;
    float den = fmaxf(1.0f + 2.0f * xy + x2s * y2, EPSV);
    float hj = (ca * mv + cb * hb) / den;
    float hn = fmaxf(sqrtf(wredsum(hj * hj)), EPSV);
    if (hn > MAXN) { hj *= MAXN / hn; hn = MAXN; }
    return (artanh_(hn) / hn) * hj;
}

__device__ __forceinline__ float agg_transform(float a, float* xn_out) {
    float n = fmaxf(sqrtf(wredsum(a * a)), EPSV);
    float th = tanhf(n);
    float g = th / n;
    float nh = fmaxf(th, EPSV);
    if (nh > MAXN) { g *= MAXN / nh; nh = MAXN; }
    float h = g * a;
    float t = fmaxf((artanh_(nh) / nh) * h, 0.0f);
    float n2 = fmaxf(sqrtf(wredsum(t * t)), EPSV);
    float th2 = tanhf(n2);
    float g2 = th2 / n2;
    float nh2 = fmaxf(th2, EPSV);
    if (nh2 > MAXN) { g2 *= MAXN / nh2; nh2 = MAXN; }
    *xn_out = nh2;
    return g2 * t;
}

__device__ __forceinline__ float bias_point(const float* bv, int lane, float* y2) {
    float b = bv[lane];
    float bn = fmaxf(sqrtf(wredsum(b * b)), EPSV);
    float gs = tanhf(bn) / bn;
    float hbn = fmaxf(tanhf(bn), EPSV);
    if (hbn > MAXN) gs *= MAXN / hbn;
    float hb = gs * b;
    *y2 = wredsum(hb * hb);
    return hb;
}

__global__ __launch_bounds__(256) void hg8_zero(float* __restrict__ p, int n4) {
    const float4 z = make_float4(0.f, 0.f, 0.f, 0.f);
    int stride = gridDim.x * blockDim.x;
    for (int i = blockIdx.x * blockDim.x + threadIdx.x; i < n4; i += stride)
        ((float4*)p)[i] = z;
}

// ===== layer 1: MFMA GEMM (round-6/7 proven, unchanged) =====
__global__ __launch_bounds__(256) void hg8_layer1(
    const float* __restrict__ x,     // [N,256]
    const float* __restrict__ W1,    // [64,256] row-major
    const float* __restrict__ b1v,   // [64]
    float* __restrict__ xt, int N)
{
    const int tid = threadIdx.x, lane = tid & 63, wv = tid >> 6;
    const int nodeBase = (blockIdx.x * 4 + wv) * 16;
    if (nodeBase >= N) return;

    float y2;
    float hb = bias_point(b1v, lane, &y2);
    float hbv[4];
#pragma unroll
    for (int t = 0; t < 4; ++t) hbv[t] = __shfl(hb, (lane & 15) + 16 * t);

    const int m = lane & 15, q = lane >> 4;
    v4f acc0 = {0,0,0,0}, acc1 = {0,0,0,0}, acc2 = {0,0,0,0}, acc3 = {0,0,0,0};
    float usq = 0.0f;

    const float* arow = x + (size_t)(nodeBase + m) * 256 + q * 8;
#pragma unroll
    for (int s = 0; s < 8; ++s) {
        float af[8];
        *(float4*)(af)     = *(const float4*)(arow + s * 32);
        *(float4*)(af + 4) = *(const float4*)(arow + s * 32 + 4);
#pragma unroll
        for (int j = 0; j < 8; ++j) usq = fmaf(af[j], af[j], usq);
        v8s a = cvt8(af);
        const float* wbase = W1 + (size_t)m * 256 + s * 32 + q * 8;
        float wf[8];
        *(float4*)(wf) = *(const float4*)(wbase);
        *(float4*)(wf + 4) = *(const float4*)(wbase + 4);
        acc0 = __builtin_amdgcn_mfma_f32_16x16x32_bf16(a, cvt8(wf), acc0, 0, 0, 0);
        *(float4*)(wf) = *(const float4*)(wbase + 16 * 256);
        *(float4*)(wf + 4) = *(const float4*)(wbase + 16 * 256 + 4);
        acc1 = __builtin_amdgcn_mfma_f32_16x16x32_bf16(a, cvt8(wf), acc1, 0, 0, 0);
        *(float4*)(wf) = *(const float4*)(wbase + 32 * 256);
        *(float4*)(wf + 4) = *(const float4*)(wbase + 32 * 256 + 4);
        acc2 = __builtin_amdgcn_mfma_f32_16x16x32_bf16(a, cvt8(wf), acc2, 0, 0, 0);
        *(float4*)(wf) = *(const float4*)(wbase + 48 * 256);
        *(float4*)(wf + 4) = *(const float4*)(wbase + 48 * 256 + 4);
        acc3 = __builtin_amdgcn_mfma_f32_16x16x32_bf16(a, cvt8(wf), acc3, 0, 0, 0);
    }
    usq += __shfl_xor(usq, 16, 64);
    usq += __shfl_xor(usq, 32, 64);

    float P[4], Q[4];
#pragma unroll
    for (int r = 0; r < 4; ++r) {
        float s2 = acc0[r]*acc0[r] + acc1[r]*acc1[r] + acc2[r]*acc2[r] + acc3[r]*acc3[r];
        float sh = acc0[r]*hbv[0] + acc1[r]*hbv[1] + acc2[r]*hbv[2] + acc3[r]*hbv[3];
#pragma unroll
        for (int o = 1; o < 16; o <<= 1) {
            s2 += __shfl_xor(s2, o, 64);
            sh += __shfl_xor(sh, o, 64);
        }
        float usq_r = __shfl(usq, q * 4 + r);
        float n  = fmaxf(sqrtf(usq_r), EPSV);
        float th = tanhf(n);
        float gamma = th / n;
        float xn = fmaxf(th, EPSV);
        if (xn > MAXN) { gamma *= MAXN / xn; xn = MAXN; }
        float mxn = fmaxf(gamma * sqrtf(s2), EPSV);
        float rt  = tanhf(mxn / xn * artanh_(xn));
        float k1, x2s, xy;
        if (s2 != 0.0f) {
            k1 = (rt / mxn) * gamma;
            float mvn = fmaxf(fabsf(rt), EPSV);
            if (mvn > MAXN) k1 *= MAXN / mvn;
            float cn = fminf(mvn, MAXN);
            x2s = cn * cn;
            xy  = k1 * sh;
        } else { k1 = 0.0f; x2s = 0.0f; xy = 0.0f; }
        float ca = 1.0f + 2.0f * xy + y2;
        float cb = 1.0f - x2s;
        float den = fmaxf(1.0f + 2.0f * xy + x2s * y2, EPSV);
        float hn2 = ca*ca*x2s + 2.0f*ca*cb*xy + cb*cb*y2;
        float hn = fmaxf(sqrtf(hn2) / den, EPSV);
        float hs = 1.0f;
        if (hn > MAXN) { hs = MAXN / hn; hn = MAXN; }
        float lam = artanh_(hn) / hn;
        P[r] = lam * hs * ca * k1 / den;
        Q[r] = lam * hs * cb / den;
    }
#pragma unroll
    for (int r = 0; r < 4; ++r) {
        float* orow = xt + (size_t)(nodeBase + q * 4 + r) * 64 + m;
        orow[ 0] = P[r] * acc0[r] + Q[r] * hbv[0];
        orow[16] = P[r] * acc1[r] + Q[r] * hbv[1];
        orow[32] = P[r] * acc2[r] + Q[r] * hbv[2];
        orow[48] = P[r] * acc3[r] + Q[r] * hbv[3];
    }
}

// ===== CSR build (round-7 proven) =====
__global__ __launch_bounds__(256) void hg8_zero_i32(int* __restrict__ p, int n) {
    int stride = gridDim.x * blockDim.x;
    for (int i = blockIdx.x * blockDim.x + threadIdx.x; i < n; i += stride) p[i] = 0;
}

__global__ __launch_bounds__(256) void hg8_count(
    const int* __restrict__ dst, int* __restrict__ deg, int E) {
    int stride = gridDim.x * blockDim.x;
    for (int e = blockIdx.x * blockDim.x + threadIdx.x; e < E; e += stride)
        atomicAdd(&deg[dst[e]], 1);
}

__global__ __launch_bounds__(1024) void hg8_scan(
    const int* __restrict__ deg, int* __restrict__ row_start,
    int* __restrict__ cursor, int N) {
    __shared__ int wsum[16];
    __shared__ int srun;
    const int tid = threadIdx.x, lane = tid & 63, wv = tid >> 6;
    if (tid == 0) srun = 0;
    __syncthreads();
    for (int base = 0; base < N; base += 1024) {
        int i = base + tid;
        int v = (i < N) ? deg[i] : 0;
        int incl = v;
#pragma unroll
        for (int o = 1; o < 64; o <<= 1) {
            int nbr = __shfl_up(incl, o, 64);
            if (lane >= o) incl += nbr;
        }
        if (lane == 63) wsum[wv] = incl;
        __syncthreads();
        int add = 0;
#pragma unroll
        for (int w = 0; w < 16; ++w) { int s = wsum[w]; if (w < wv) add += s; }
        int excl = srun + add + incl - v;
        if (i < N) { row_start[i] = excl; cursor[i] = excl; }
        __syncthreads();
        if (tid == 1023) srun += add + incl;
        __syncthreads();
    }
    if (tid == 0) row_start[N] = srun;
}

__global__ __launch_bounds__(256) void hg8_fill(
    const int* __restrict__ src, const int* __restrict__ dst,
    const float* __restrict__ ew, int* __restrict__ cursor,
    int* __restrict__ csr_src, float* __restrict__ csr_w, int E) {
    int stride = gridDim.x * blockDim.x;
    for (int e = blockIdx.x * blockDim.x + threadIdx.x; e < E; e += stride) {
        int d = dst[e];
        int slot = atomicAdd(&cursor[d], 1);
        csr_src[slot] = src[e];
        csr_w[slot]   = ew[e];
    }
}

// ===== gather #1: agg[d] = sum w*xt[src] (round-7 proven) =====
__global__ __launch_bounds__(256) void hg8_gather(
    const int* __restrict__ row_start, const int* __restrict__ csr_src,
    const float* __restrict__ csr_w, const float* __restrict__ xt,
    float* __restrict__ agg, int N) {
    const int lane = threadIdx.x & 63, wv = threadIdx.x >> 6;
    const int d = blockIdx.x * 4 + wv;
    if (d >= N) return;
    const int n0 = row_start[d], n1 = row_start[d + 1];
    float acc = 0.0f;
    for (int base = n0; base < n1; base += 64) {
        int cnt = n1 - base; if (cnt > 64) cnt = 64;
        int   sL = 0; float wL = 0.0f;
        if (lane < cnt) { sL = csr_src[base + lane]; wL = csr_w[base + lane]; }
        for (int j = 0; j < cnt; ++j) {
            int s = __shfl(sL, j);
            float w = __shfl(wL, j);
            acc = fmaf(w, xt[(size_t)s * 64 + lane], acc);
        }
    }
    agg[(size_t)d * 64 + lane] = acc;
}

// ===== layer 2: MFMA, fused HypAct + matvec + tail, IN-PLACE on agg =====
__global__ __launch_bounds__(256) void hg8_layer2_mfma(
    float* __restrict__ agg,         // [N,64] read a, write xt2 (same rows)
    const float* __restrict__ W2,    // [64,64] row-major
    const float* __restrict__ b2v,   // [64]
    int N)
{
    const int tid = threadIdx.x, lane = tid & 63, wv = tid >> 6;
    const int nodeBase = (blockIdx.x * 4 + wv) * 16;
    if (nodeBase >= N) return;

    float y2;
    float hb = bias_point(b2v, lane, &y2);
    float hbv[4];
#pragma unroll
    for (int t = 0; t < 4; ++t) hbv[t] = __shfl(hb, (lane & 15) + 16 * t);

    const int m = lane & 15, q = lane >> 4;
    const bool rowok = (nodeBase + m) < N;

    // A-layout load: lane (m,q) holds a[row m][k = 32s + 8q + j]
    float af0[8], af1[8];
    const float* arow = agg + (size_t)(nodeBase + m) * 64 + q * 8;
    if (rowok) {
        *(float4*)(af0)     = *(const float4*)(arow);
        *(float4*)(af0 + 4) = *(const float4*)(arow + 4);
        *(float4*)(af1)     = *(const float4*)(arow + 32);
        *(float4*)(af1 + 4) = *(const float4*)(arow + 36);
    } else {
#pragma unroll
        for (int j = 0; j < 8; ++j) { af0[j] = 0.0f; af1[j] = 0.0f; }
    }
    float asq = 0.0f;
#pragma unroll
    for (int j = 0; j < 8; ++j) {
        asq = fmaf(af0[j], af0[j], asq);
        asq = fmaf(af1[j], af1[j], asq);
    }
    asq += __shfl_xor(asq, 16, 64);
    asq += __shfl_xor(asq, 32, 64);          // row-m sumsq on all 4 q-lanes

    // agg_transform (HypAct), per-row scalars + elementwise relu chain
    float n  = fmaxf(sqrtf(asq), EPSV);
    float th = tanhf(n);
    float g  = th / n;
    float nh = fmaxf(th, EPSV);
    if (nh > MAXN) { g *= MAXN / nh; nh = MAXN; }
    float lamg = (artanh_(nh) / nh) * g;     // t = relu(lamg * a)
    float t0[8], t1[8], tsq = 0.0f;
#pragma unroll
    for (int j = 0; j < 8; ++j) {
        t0[j] = fmaxf(lamg * af0[j], 0.0f);
        t1[j] = fmaxf(lamg * af1[j], 0.0f);
        tsq = fmaf(t0[j], t0[j], tsq);
        tsq = fmaf(t1[j], t1[j], tsq);
    }
    tsq += __shfl_xor(tsq, 16, 64);
    tsq += __shfl_xor(tsq, 32, 64);
    float n2  = fmaxf(sqrtf(tsq), EPSV);
    float th2 = tanhf(n2);
    float g2  = th2 / n2;
    float nh2 = fmaxf(th2, EPSV);
    if (nh2 > MAXN) { g2 *= MAXN / nh2; nh2 = MAXN; }
    float xn_m = nh2;                        // ||x2|| of row m (analytic)
    float x0[8], x1[8];
#pragma unroll
    for (int j = 0; j < 8; ++j) { x0[j] = g2 * t0[j]; x1[j] = g2 * t1[j]; }
    v8s a0 = cvt8(x0), a1 = cvt8(x1);

    // matvec x2 @ W2^T: K=64 -> 2 MFMA steps x 4 column tiles
    v4f acc0 = {0,0,0,0}, acc1 = {0,0,0,0}, acc2 = {0,0,0,0}, acc3 = {0,0,0,0};
    {
        float wf[8];
        const float* wb;
        wb = W2 + (size_t)(m     ) * 64 + q * 8;
        *(float4*)(wf) = *(const float4*)(wb);     *(float4*)(wf+4) = *(const float4*)(wb+4);
        acc0 = __builtin_amdgcn_mfma_f32_16x16x32_bf16(a0, cvt8(wf), acc0, 0, 0, 0);
        *(float4*)(wf) = *(const float4*)(wb+32);  *(float4*)(wf+4) = *(const float4*)(wb+36);
        acc0 = __builtin_amdgcn_mfma_f32_16x16x32_bf16(a1, cvt8(wf), acc0, 0, 0, 0);
        wb = W2 + (size_t)(m + 16) * 64 + q * 8;
        *(float4*)(wf) = *(const float4*)(wb);     *(float4*)(wf+4) = *(const float4*)(wb+4);
        acc1 = __builtin_amdgcn_mfma_f32_16x16x32_bf16(a0, cvt8(wf), acc1, 0, 0, 0);
        *(float4*)(wf) = *(const float4*)(wb+32);  *(float4*)(wf+4) = *(const float4*)(wb+36);
        acc1 = __builtin_amdgcn_mfma_f32_16x16x32_bf16(a1, cvt8(wf), acc1, 0, 0, 0);
        wb = W2 + (size_t)(m + 32) * 64 + q * 8;
        *(float4*)(wf) = *(const float4*)(wb);     *(float4*)(wf+4) = *(const float4*)(wb+4);
        acc2 = __builtin_amdgcn_mfma_f32_16x16x32_bf16(a0, cvt8(wf), acc2, 0, 0, 0);
        *(float4*)(wf) = *(const float4*)(wb+32);  *(float4*)(wf+4) = *(const float4*)(wb+36);
        acc2 = __builtin_amdgcn_mfma_f32_16x16x32_bf16(a1, cvt8(wf), acc2, 0, 0, 0);
        wb = W2 + (size_t)(m + 48) * 64 + q * 8;
        *(float4*)(wf) = *(const float4*)(wb);     *(float4*)(wf+4) = *(const float4*)(wb+4);
        acc3 = __builtin_amdgcn_mfma_f32_16x16x32_bf16(a0, cvt8(wf), acc3, 0, 0, 0);
        *(float4*)(wf) = *(const float4*)(wb+32);  *(float4*)(wf+4) = *(const float4*)(wb+36);
        acc3 = __builtin_amdgcn_mfma_f32_16x16x32_bf16(a1, cvt8(wf), acc3, 0, 0, 0);
    }

    // epilogue: C row = 4q + r, col = m + 16t (gamma = 1, xn from transform)
    float P[4], Q[4];
#pragma unroll
    for (int r = 0; r < 4; ++r) {
        float s2 = acc0[r]*acc0[r] + acc1[r]*acc1[r] + acc2[r]*acc2[r] + acc3[r]*acc3[r];
        float sh = acc0[r]*hbv[0] + acc1[r]*hbv[1] + acc2[r]*hbv[2] + acc3[r]*hbv[3];
#pragma unroll
        for (int o = 1; o < 16; o <<= 1) {
            s2 += __shfl_xor(s2, o, 64);
            sh += __shfl_xor(sh, o, 64);
        }
        float xn = __shfl(xn_m, q * 4 + r);      // ||x2|| of C-row 4q+r
        float mxn = fmaxf(sqrtf(s2), EPSV);
        float rt  = tanhf(mxn / xn * artanh_(xn));
        float k1, x2s, xy;
        if (s2 != 0.0f) {
            k1 = rt / mxn;
            float mvn = fmaxf(fabsf(rt), EPSV);
            if (mvn > MAXN) k1 *= MAXN / mvn;
            float cn = fminf(mvn, MAXN);
            x2s = cn * cn;
            xy  = k1 * sh;
        } else { k1 = 0.0f; x2s = 0.0f; xy = 0.0f; }
        float ca = 1.0f + 2.0f * xy + y2;
        float cb = 1.0f - x2s;
        float den = fmaxf(1.0f + 2.0f * xy + x2s * y2, EPSV);
        float hn2 = ca*ca*x2s + 2.0f*ca*cb*xy + cb*cb*y2;
        float hn = fmaxf(sqrtf(hn2) / den, EPSV);
        float hs = 1.0f;
        if (hn > MAXN) { hs = MAXN / hn; hn = MAXN; }
        float lam = artanh_(hn) / hn;
        P[r] = lam * hs * ca * k1 / den;
        Q[r] = lam * hs * cb / den;
    }
#pragma unroll
    for (int r = 0; r < 4; ++r) {
        int ri = nodeBase + q * 4 + r;
        if (ri < N) {
            float* orow = agg + (size_t)ri * 64 + m;   // in-place write
            orow[ 0] = P[r] * acc0[r] + Q[r] * hbv[0];
            orow[16] = P[r] * acc1[r] + Q[r] * hbv[1];
            orow[32] = P[r] * acc2[r] + Q[r] * hbv[2];
            orow[48] = P[r] * acc3[r] + Q[r] * hbv[3];
        }
    }
}

// ===== gather #2 fused with final HypAct: out[d] = transform(sum w*xt2[src]) =====
__global__ __launch_bounds__(256) void hg8_gather_out(
    const int* __restrict__ row_start, const int* __restrict__ csr_src,
    const float* __restrict__ csr_w, const float* __restrict__ xt2,
    float* __restrict__ out, int N) {
    const int lane = threadIdx.x & 63, wv = threadIdx.x >> 6;
    const int d = blockIdx.x * 4 + wv;
    if (d >= N) return;
    const int n0 = row_start[d], n1 = row_start[d + 1];
    float acc = 0.0f;
    for (int base = n0; base < n1; base += 64) {
        int cnt = n1 - base; if (cnt > 64) cnt = 64;
        int   sL = 0; float wL = 0.0f;
        if (lane < cnt) { sL = csr_src[base + lane]; wL = csr_w[base + lane]; }
        for (int j = 0; j < cnt; ++j) {
            int s = __shfl(sL, j);
            float w = __shfl(wL, j);
            acc = fmaf(w, xt2[(size_t)s * 64 + lane], acc);
        }
    }
    float xn;
    float o = agg_transform(acc, &xn);
    out[(size_t)d * 64 + lane] = o;
}

// ===== fallback kernels (round-7 proven, used only if ws too small) =====
__global__ __launch_bounds__(256) void hg8_scatter(
    const int* __restrict__ src, const int* __restrict__ dst,
    const float* __restrict__ ew,
    const float* __restrict__ xt, float* __restrict__ agg, int E)
{
    const int lane = threadIdx.x & 63;
    const long long wid = ((long long)blockIdx.x * blockDim.x + threadIdx.x) >> 6;
    const long long nw = ((long long)gridDim.x * blockDim.x) >> 6;
    for (long long e = wid; e < E; e += nw) {
        int s = src[e], d = dst[e];
        atomicAdd(&agg[(size_t)d * 64 + lane], ew[e] * xt[(size_t)s * 64 + lane]);
    }
}

__global__ __launch_bounds__(256) void hg8_layer2_fb(
    const float* __restrict__ agg,
    const float* __restrict__ W2, const float* __restrict__ b2v,
    float* __restrict__ xt2, int N)
{
    const int lane = threadIdx.x & 63, wv = threadIdx.x >> 6;
    float y2;
    float hb = bias_point(b2v, lane, &y2);
    const int nw = gridDim.x * 4;
    for (int i = blockIdx.x * 4 + wv; i < N; i += nw) {
        float a = agg[(size_t)i * 64 + lane];
        float xn;
        float x2 = agg_transform(a, &xn);
        float acc = 0.0f;
        const float* Wrow = W2 + (size_t)lane * 64;
        for (int s = 0; s < 64; ++s)
            acc = fmaf(__shfl(x2, s), Wrow[s], acc);
        float o = mobius_tail(acc, xn, hb, y2);
        xt2[(size_t)i * 64 + lane] = o;
    }
}

__global__ __launch_bounds__(256) void hg8_final_fb(
    const float* __restrict__ agg, float* __restrict__ out, int N)
{
    const int lane = threadIdx.x & 63, wv = threadIdx.x >> 6;
    const int nw = gridDim.x * 4;
    for (int i = blockIdx.x * 4 + wv; i < N; i += nw) {
        float a = agg[(size_t)i * 64 + lane];
        float xn;
        float o = agg_transform(a, &xn);
        out[(size_t)i * 64 + lane] = o;
    }
}

extern "C" void kernel_launch(void* const* d_in, const int* in_sizes, int n_in,
                              void* d_out, int out_size, void* d_ws, size_t ws_size,
                              hipStream_t stream)
{
    const float* x  = (const float*)d_in[0];
    const int* src  = (const int*)d_in[1];
    const int* dst  = (const int*)d_in[2];
    const float* ew = (const float*)d_in[3];
    const float* W1 = (const float*)d_in[4];
    const float* b1 = (const float*)d_in[5];
    const float* W2 = (const float*)d_in[6];
    const float* b2 = (const float*)d_in[7];

    const int Dd = in_sizes[5];            // 64
    const int Ff = in_sizes[4] / Dd;       // 256
    const int N  = in_sizes[0] / Ff;       // 80000
    const int E  = in_sizes[1];            // 1280000

    float* out  = (float*)d_out;
    float* xt   = (float*)d_out;           // [N,64] layer-1 tangent scratch

    // d_ws: [agg f32 N*64][deg N][row_start N+1][cursor N][csr_src E][csr_w E]
    float* agg     = (float*)d_ws;
    int*   deg     = (int*)(agg + (size_t)N * Dd);
    int*   rowst   = deg + N;
    int*   cursor  = rowst + (N + 1);
    int*   csr_src = cursor + N;
    float* csr_w   = (float*)(csr_src + E);
    const size_t ws_need = (size_t)N * Dd * 4 + (size_t)(3 * N + 1) * 4 + (size_t)E * 8;
    const bool use_csr = ws_size >= ws_need;

    const int blkT = (N + 63) / 64;        // wave per 16 nodes (layer1/layer2)
    const int blkG = (N + 3) / 4;          // wave per dst node (gathers)
    const int n4   = (N * Dd) / 4;

    hg8_layer1<<<blkT, 256, 0, stream>>>(x, W1, b1, xt, N);
    if (use_csr) {
        hg8_zero_i32   <<<128,  256, 0, stream>>>(deg, N);
        hg8_count      <<<2048, 256, 0, stream>>>(dst, deg, E);
        hg8_scan       <<<1,   1024, 0, stream>>>(deg, rowst, cursor, N);
        hg8_fill       <<<2048, 256, 0, stream>>>(src, dst, ew, cursor, csr_src, csr_w, E);
        hg8_gather     <<<blkG, 256, 0, stream>>>(rowst, csr_src, csr_w, xt, agg, N);
        hg8_layer2_mfma<<<blkT, 256, 0, stream>>>(agg, W2, b2, N);          // in-place
        hg8_gather_out <<<blkG, 256, 0, stream>>>(rowst, csr_src, csr_w, agg, out, N);
    } else {
        hg8_zero     <<<1024,  256, 0, stream>>>(agg, n4);
        hg8_scatter  <<<16384, 256, 0, stream>>>(src, dst, ew, xt, agg, E);
        hg8_layer2_fb<<<2048,  256, 0, stream>>>(agg, W2, b2, xt, N);
        hg8_zero     <<<1024,  256, 0, stream>>>(agg, n4);
        hg8_scatter  <<<16384, 256, 0, stream>>>(src, dst, ew, xt, agg, E);
        hg8_final_fb <<<2048,  256, 0, stream>>>(agg, out, N);
    }
}

// Round 9
// 516.444 us; speedup vs baseline: 2.7493x; 1.1257x over previous
//
#include <hip/hip_runtime.h>

// HGCN forward (2-layer hyperbolic GCN), Poincare ball c=1. fp32 in/out
// (values bf16-grid). Round 9 = round 8 with (a) CSR records packed as
// int2{src,w_bits} -> single 8B scattered store in fill (was 2x4B into two
// arrays, 12x write amplification), (b) 4-way ILP accumulators in gathers.
// layer1 / CSR count+scan / layer2-MFMA / fused gather_out otherwise as in
// round 8 (proven). Non-CSR fallback = round-7 path verbatim.

#define EPSV 1e-15f
#define MAXN 0.996f   // (1 - 4e-3) / sqrt(c), c = 1

typedef unsigned short bfu;
typedef __attribute__((ext_vector_type(8))) short v8s;   // 8 bf16 (4 VGPRs)
typedef __attribute__((ext_vector_type(4))) float v4f;   // MFMA acc

__device__ __forceinline__ bfu f2b(float f) {   // fp32 -> bf16, RNE
    unsigned int u;
    __builtin_memcpy(&u, &f, sizeof(u));
    u += 0x7fffu + ((u >> 16) & 1u);
    return (bfu)(u >> 16);
}

__device__ __forceinline__ v8s cvt8(const float* f) {
    v8s r;
#pragma unroll
    for (int j = 0; j < 8; ++j) r[j] = (short)f2b(f[j]);
    return r;
}

__device__ __forceinline__ float i2f(int i) {
    float f; __builtin_memcpy(&f, &i, sizeof(f)); return f;
}
__device__ __forceinline__ int f2i(float f) {
    int i; __builtin_memcpy(&i, &f, sizeof(i)); return i;
}

__device__ __forceinline__ float wredsum(float v) {
#pragma unroll
    for (int o = 32; o > 0; o >>= 1) v += __shfl_xor(v, o, 64);
    return v;
}

__device__ __forceinline__ float artanh_(float x) {
    x = fminf(fmaxf(x, -1.0f + 1e-7f), 1.0f - 1e-7f);
    return 0.5f * logf((1.0f + x) / (1.0f - x));
}

__device__ __forceinline__ float mobius_tail(float mx, float xn, float hb, float y2) {
    float mxn2 = wredsum(mx * mx);
    unsigned long long nz = __ballot(mx != 0.0f);
    float mxn = fmaxf(sqrtf(mxn2), EPSV);
    float rt = tanhf(mxn / xn * artanh_(xn));
    float mv, x2s;
    if (nz != 0ull) {
        mv = (rt / mxn) * mx;
        float mvn = fmaxf(fabsf(rt), EPSV);
        if (mvn > MAXN) mv *= MAXN / mvn;
        float cn = fminf(mvn, MAXN);
        x2s = cn * cn;
    } else { mv = 0.0f; x2s = 0.0f; }
    float xy = wredsum(mv * hb);
    float ca = 1.0f + 2.0f * xy + y2;
    float cb = 1.0f - x2s;
    float den = fmaxf(1.0f + 2.0f * xy + x2s * y2, EPSV);
    float hj = (ca * mv + cb * hb) / den;
    float hn = fmaxf(sqrtf(wredsum(hj * hj)), EPSV);
    if (hn > MAXN) { hj *= MAXN / hn; hn = MAXN; }
    return (artanh_(hn) / hn) * hj;
}

__device__ __forceinline__ float agg_transform(float a, float* xn_out) {
    float n = fmaxf(sqrtf(wredsum(a * a)), EPSV);
    float th = tanhf(n);
    float g = th / n;
    float nh = fmaxf(th, EPSV);
    if (nh > MAXN) { g *= MAXN / nh; nh = MAXN; }
    float h = g * a;
    float t = fmaxf((artanh_(nh) / nh) * h, 0.0f);
    float n2 = fmaxf(sqrtf(wredsum(t * t)), EPSV);
    float th2 = tanhf(n2);
    float g2 = th2 / n2;
    float nh2 = fmaxf(th2, EPSV);
    if (nh2 > MAXN) { g2 *= MAXN / nh2; nh2 = MAXN; }
    *xn_out = nh2;
    return g2 * t;
}

__device__ __forceinline__ float bias_point(const float* bv, int lane, float* y2) {
    float b = bv[lane];
    float bn = fmaxf(sqrtf(wredsum(b * b)), EPSV);
    float gs = tanhf(bn) / bn;
    float hbn = fmaxf(tanhf(bn), EPSV);
    if (hbn > MAXN) gs *= MAXN / hbn;
    float hb = gs * b;
    *y2 = wredsum(hb * hb);
    return hb;
}

__global__ __launch_bounds__(256) void hg9_zero(float* __restrict__ p, int n4) {
    const float4 z = make_float4(0.f, 0.f, 0.f, 0.f);
    int stride = gridDim.x * blockDim.x;
    for (int i = blockIdx.x * blockDim.x + threadIdx.x; i < n4; i += stride)
        ((float4*)p)[i] = z;
}

// ===== layer 1: MFMA GEMM (proven) =====
__global__ __launch_bounds__(256) void hg9_layer1(
    const float* __restrict__ x,     // [N,256]
    const float* __restrict__ W1,    // [64,256] row-major
    const float* __restrict__ b1v,   // [64]
    float* __restrict__ xt, int N)
{
    const int tid = threadIdx.x, lane = tid & 63, wv = tid >> 6;
    const int nodeBase = (blockIdx.x * 4 + wv) * 16;
    if (nodeBase >= N) return;

    float y2;
    float hb = bias_point(b1v, lane, &y2);
    float hbv[4];
#pragma unroll
    for (int t = 0; t < 4; ++t) hbv[t] = __shfl(hb, (lane & 15) + 16 * t);

    const int m = lane & 15, q = lane >> 4;
    v4f acc0 = {0,0,0,0}, acc1 = {0,0,0,0}, acc2 = {0,0,0,0}, acc3 = {0,0,0,0};
    float usq = 0.0f;

    const float* arow = x + (size_t)(nodeBase + m) * 256 + q * 8;
#pragma unroll
    for (int s = 0; s < 8; ++s) {
        float af[8];
        *(float4*)(af)     = *(const float4*)(arow + s * 32);
        *(float4*)(af + 4) = *(const float4*)(arow + s * 32 + 4);
#pragma unroll
        for (int j = 0; j < 8; ++j) usq = fmaf(af[j], af[j], usq);
        v8s a = cvt8(af);
        const float* wbase = W1 + (size_t)m * 256 + s * 32 + q * 8;
        float wf[8];
        *(float4*)(wf) = *(const float4*)(wbase);
        *(float4*)(wf + 4) = *(const float4*)(wbase + 4);
        acc0 = __builtin_amdgcn_mfma_f32_16x16x32_bf16(a, cvt8(wf), acc0, 0, 0, 0);
        *(float4*)(wf) = *(const float4*)(wbase + 16 * 256);
        *(float4*)(wf + 4) = *(const float4*)(wbase + 16 * 256 + 4);
        acc1 = __builtin_amdgcn_mfma_f32_16x16x32_bf16(a, cvt8(wf), acc1, 0, 0, 0);
        *(float4*)(wf) = *(const float4*)(wbase + 32 * 256);
        *(float4*)(wf + 4) = *(const float4*)(wbase + 32 * 256 + 4);
        acc2 = __builtin_amdgcn_mfma_f32_16x16x32_bf16(a, cvt8(wf), acc2, 0, 0, 0);
        *(float4*)(wf) = *(const float4*)(wbase + 48 * 256);
        *(float4*)(wf + 4) = *(const float4*)(wbase + 48 * 256 + 4);
        acc3 = __builtin_amdgcn_mfma_f32_16x16x32_bf16(a, cvt8(wf), acc3, 0, 0, 0);
    }
    usq += __shfl_xor(usq, 16, 64);
    usq += __shfl_xor(usq, 32, 64);

    float P[4], Q[4];
#pragma unroll
    for (int r = 0; r < 4; ++r) {
        float s2 = acc0[r]*acc0[r] + acc1[r]*acc1[r] + acc2[r]*acc2[r] + acc3[r]*acc3[r];
        float sh = acc0[r]*hbv[0] + acc1[r]*hbv[1] + acc2[r]*hbv[2] + acc3[r]*hbv[3];
#pragma unroll
        for (int o = 1; o < 16; o <<= 1) {
            s2 += __shfl_xor(s2, o, 64);
            sh += __shfl_xor(sh, o, 64);
        }
        float usq_r = __shfl(usq, q * 4 + r);
        float n  = fmaxf(sqrtf(usq_r), EPSV);
        float th = tanhf(n);
        float gamma = th / n;
        float xn = fmaxf(th, EPSV);
        if (xn > MAXN) { gamma *= MAXN / xn; xn = MAXN; }
        float mxn = fmaxf(gamma * sqrtf(s2), EPSV);
        float rt  = tanhf(mxn / xn * artanh_(xn));
        float k1, x2s, xy;
        if (s2 != 0.0f) {
            k1 = (rt / mxn) * gamma;
            float mvn = fmaxf(fabsf(rt), EPSV);
            if (mvn > MAXN) k1 *= MAXN / mvn;
            float cn = fminf(mvn, MAXN);
            x2s = cn * cn;
            xy  = k1 * sh;
        } else { k1 = 0.0f; x2s = 0.0f; xy = 0.0f; }
        float ca = 1.0f + 2.0f * xy + y2;
        float cb = 1.0f - x2s;
        float den = fmaxf(1.0f + 2.0f * xy + x2s * y2, EPSV);
        float hn2 = ca*ca*x2s + 2.0f*ca*cb*xy + cb*cb*y2;
        float hn = fmaxf(sqrtf(hn2) / den, EPSV);
        float hs = 1.0f;
        if (hn > MAXN) { hs = MAXN / hn; hn = MAXN; }
        float lam = artanh_(hn) / hn;
        P[r] = lam * hs * ca * k1 / den;
        Q[r] = lam * hs * cb / den;
    }
#pragma unroll
    for (int r = 0; r < 4; ++r) {
        float* orow = xt + (size_t)(nodeBase + q * 4 + r) * 64 + m;
        orow[ 0] = P[r] * acc0[r] + Q[r] * hbv[0];
        orow[16] = P[r] * acc1[r] + Q[r] * hbv[1];
        orow[32] = P[r] * acc2[r] + Q[r] * hbv[2];
        orow[48] = P[r] * acc3[r] + Q[r] * hbv[3];
    }
}

// ===== CSR build =====
__global__ __launch_bounds__(256) void hg9_zero_i32(int* __restrict__ p, int n) {
    int stride = gridDim.x * blockDim.x;
    for (int i = blockIdx.x * blockDim.x + threadIdx.x; i < n; i += stride) p[i] = 0;
}

__global__ __launch_bounds__(256) void hg9_count(
    const int* __restrict__ dst, int* __restrict__ deg, int E) {
    int stride = gridDim.x * blockDim.x;
    for (int e = blockIdx.x * blockDim.x + threadIdx.x; e < E; e += stride)
        atomicAdd(&deg[dst[e]], 1);
}

__global__ __launch_bounds__(1024) void hg9_scan(
    const int* __restrict__ deg, int* __restrict__ row_start,
    int* __restrict__ cursor, int N) {
    __shared__ int wsum[16];
    __shared__ int srun;
    const int tid = threadIdx.x, lane = tid & 63, wv = tid >> 6;
    if (tid == 0) srun = 0;
    __syncthreads();
    for (int base = 0; base < N; base += 1024) {
        int i = base + tid;
        int v = (i < N) ? deg[i] : 0;
        int incl = v;
#pragma unroll
        for (int o = 1; o < 64; o <<= 1) {
            int nbr = __shfl_up(incl, o, 64);
            if (lane >= o) incl += nbr;
        }
        if (lane == 63) wsum[wv] = incl;
        __syncthreads();
        int add = 0;
#pragma unroll
        for (int w = 0; w < 16; ++w) { int s = wsum[w]; if (w < wv) add += s; }
        int excl = srun + add + incl - v;
        if (i < N) { row_start[i] = excl; cursor[i] = excl; }
        __syncthreads();
        if (tid == 1023) srun += add + incl;
        __syncthreads();
    }
    if (tid == 0) row_start[N] = srun;
}

// fill: ONE 8B record per edge (src, weight-bits) -> half the scattered lines
__global__ __launch_bounds__(256) void hg9_fill(
    const int* __restrict__ src, const int* __restrict__ dst,
    const float* __restrict__ ew, int* __restrict__ cursor,
    int2* __restrict__ csr, int E) {
    int stride = gridDim.x * blockDim.x;
    for (int e = blockIdx.x * blockDim.x + threadIdx.x; e < E; e += stride) {
        int d = dst[e];
        int slot = atomicAdd(&cursor[d], 1);
        csr[slot] = make_int2(src[e], f2i(ew[e]));
    }
}

// ===== gather #1: agg[d] = sum w*xt[src]; 4-way ILP accumulators =====
__global__ __launch_bounds__(256) void hg9_gather(
    const int* __restrict__ row_start, const int2* __restrict__ csr,
    const float* __restrict__ xt, float* __restrict__ agg, int N) {
    const int lane = threadIdx.x & 63, wv = threadIdx.x >> 6;
    const int d = blockIdx.x * 4 + wv;
    if (d >= N) return;
    const int n0 = row_start[d], n1 = row_start[d + 1];
    float acc0 = 0.f, acc1 = 0.f, acc2 = 0.f, acc3 = 0.f;
    for (int base = n0; base < n1; base += 64) {
        int cnt = n1 - base; if (cnt > 64) cnt = 64;
        int sL = 0; float wL = 0.0f;
        if (lane < cnt) { int2 rec = csr[base + lane]; sL = rec.x; wL = i2f(rec.y); }
        int j = 0;
        for (; j + 4 <= cnt; j += 4) {
            int s0 = __shfl(sL, j),     s1 = __shfl(sL, j + 1);
            int s2 = __shfl(sL, j + 2), s3 = __shfl(sL, j + 3);
            float w0 = __shfl(wL, j),     w1 = __shfl(wL, j + 1);
            float w2 = __shfl(wL, j + 2), w3 = __shfl(wL, j + 3);
            acc0 = fmaf(w0, xt[(size_t)s0 * 64 + lane], acc0);
            acc1 = fmaf(w1, xt[(size_t)s1 * 64 + lane], acc1);
            acc2 = fmaf(w2, xt[(size_t)s2 * 64 + lane], acc2);
            acc3 = fmaf(w3, xt[(size_t)s3 * 64 + lane], acc3);
        }
        for (; j < cnt; ++j) {
            int s = __shfl(sL, j);
            float w = __shfl(wL, j);
            acc0 = fmaf(w, xt[(size_t)s * 64 + lane], acc0);
        }
    }
    agg[(size_t)d * 64 + lane] = (acc0 + acc1) + (acc2 + acc3);
}

// ===== layer 2: MFMA fused HypAct+matvec+tail, in-place (round-8 proven) =====
__global__ __launch_bounds__(256) void hg9_layer2_mfma(
    float* __restrict__ agg,         // [N,64] read a, write xt2 (same rows)
    const float* __restrict__ W2,    // [64,64] row-major
    const float* __restrict__ b2v,   // [64]
    int N)
{
    const int tid = threadIdx.x, lane = tid & 63, wv = tid >> 6;
    const int nodeBase = (blockIdx.x * 4 + wv) * 16;
    if (nodeBase >= N) return;

    float y2;
    float hb = bias_point(b2v, lane, &y2);
    float hbv[4];
#pragma unroll
    for (int t = 0; t < 4; ++t) hbv[t] = __shfl(hb, (lane & 15) + 16 * t);

    const int m = lane & 15, q = lane >> 4;
    const bool rowok = (nodeBase + m) < N;

    float af0[8], af1[8];
    const float* arow = agg + (size_t)(nodeBase + m) * 64 + q * 8;
    if (rowok) {
        *(float4*)(af0)     = *(const float4*)(arow);
        *(float4*)(af0 + 4) = *(const float4*)(arow + 4);
        *(float4*)(af1)     = *(const float4*)(arow + 32);
        *(float4*)(af1 + 4) = *(const float4*)(arow + 36);
    } else {
#pragma unroll
        for (int j = 0; j < 8; ++j) { af0[j] = 0.0f; af1[j] = 0.0f; }
    }
    float asq = 0.0f;
#pragma unroll
    for (int j = 0; j < 8; ++j) {
        asq = fmaf(af0[j], af0[j], asq);
        asq = fmaf(af1[j], af1[j], asq);
    }
    asq += __shfl_xor(asq, 16, 64);
    asq += __shfl_xor(asq, 32, 64);

    float n  = fmaxf(sqrtf(asq), EPSV);
    float th = tanhf(n);
    float g  = th / n;
    float nh = fmaxf(th, EPSV);
    if (nh > MAXN) { g *= MAXN / nh; nh = MAXN; }
    float lamg = (artanh_(nh) / nh) * g;
    float t0[8], t1[8], tsq = 0.0f;
#pragma unroll
    for (int j = 0; j < 8; ++j) {
        t0[j] = fmaxf(lamg * af0[j], 0.0f);
        t1[j] = fmaxf(lamg * af1[j], 0.0f);
        tsq = fmaf(t0[j], t0[j], tsq);
        tsq = fmaf(t1[j], t1[j], tsq);
    }
    tsq += __shfl_xor(tsq, 16, 64);
    tsq += __shfl_xor(tsq, 32, 64);
    float n2  = fmaxf(sqrtf(tsq), EPSV);
    float th2 = tanhf(n2);
    float g2  = th2 / n2;
    float nh2 = fmaxf(th2, EPSV);
    if (nh2 > MAXN) { g2 *= MAXN / nh2; nh2 = MAXN; }
    float xn_m = nh2;
    float x0[8], x1[8];
#pragma unroll
    for (int j = 0; j < 8; ++j) { x0[j] = g2 * t0[j]; x1[j] = g2 * t1[j]; }
    v8s a0 = cvt8(x0), a1 = cvt8(x1);

    v4f acc0 = {0,0,0,0}, acc1 = {0,0,0,0}, acc2 = {0,0,0,0}, acc3 = {0,0,0,0};
    {
        float wf[8];
        const float* wb;
        wb = W2 + (size_t)(m     ) * 64 + q * 8;
        *(float4*)(wf) = *(const float4*)(wb);     *(float4*)(wf+4) = *(const float4*)(wb+4);
        acc0 = __builtin_amdgcn_mfma_f32_16x16x32_bf16(a0, cvt8(wf), acc0, 0, 0, 0);
        *(float4*)(wf) = *(const float4*)(wb+32);  *(float4*)(wf+4) = *(const float4*)(wb+36);
        acc0 = __builtin_amdgcn_mfma_f32_16x16x32_bf16(a1, cvt8(wf), acc0, 0, 0, 0);
        wb = W2 + (size_t)(m + 16) * 64 + q * 8;
        *(float4*)(wf) = *(const float4*)(wb);     *(float4*)(wf+4) = *(const float4*)(wb+4);
        acc1 = __builtin_amdgcn_mfma_f32_16x16x32_bf16(a0, cvt8(wf), acc1, 0, 0, 0);
        *(float4*)(wf) = *(const float4*)(wb+32);  *(float4*)(wf+4) = *(const float4*)(wb+36);
        acc1 = __builtin_amdgcn_mfma_f32_16x16x32_bf16(a1, cvt8(wf), acc1, 0, 0, 0);
        wb = W2 + (size_t)(m + 32) * 64 + q * 8;
        *(float4*)(wf) = *(const float4*)(wb);     *(float4*)(wf+4) = *(const float4*)(wb+4);
        acc2 = __builtin_amdgcn_mfma_f32_16x16x32_bf16(a0, cvt8(wf), acc2, 0, 0, 0);
        *(float4*)(wf) = *(const float4*)(wb+32);  *(float4*)(wf+4) = *(const float4*)(wb+36);
        acc2 = __builtin_amdgcn_mfma_f32_16x16x32_bf16(a1, cvt8(wf), acc2, 0, 0, 0);
        wb = W2 + (size_t)(m + 48) * 64 + q * 8;
        *(float4*)(wf) = *(const float4*)(wb);     *(float4*)(wf+4) = *(const float4*)(wb+4);
        acc3 = __builtin_amdgcn_mfma_f32_16x16x32_bf16(a0, cvt8(wf), acc3, 0, 0, 0);
        *(float4*)(wf) = *(const float4*)(wb+32);  *(float4*)(wf+4) = *(const float4*)(wb+36);
        acc3 = __builtin_amdgcn_mfma_f32_16x16x32_bf16(a1, cvt8(wf), acc3, 0, 0, 0);
    }

    float P[4], Q[4];
#pragma unroll
    for (int r = 0; r < 4; ++r) {
        float s2 = acc0[r]*acc0[r] + acc1[r]*acc1[r] + acc2[r]*acc2[r] + acc3[r]*acc3[r];
        float sh = acc0[r]*hbv[0] + acc1[r]*hbv[1] + acc2[r]*hbv[2] + acc3[r]*hbv[3];
#pragma unroll
        for (int o = 1; o < 16; o <<= 1) {
            s2 += __shfl_xor(s2, o, 64);
            sh += __shfl_xor(sh, o, 64);
        }
        float xn = __shfl(xn_m, q * 4 + r);
        float mxn = fmaxf(sqrtf(s2), EPSV);
        float rt  = tanhf(mxn / xn * artanh_(xn));
        float k1, x2s, xy;
        if (s2 != 0.0f) {
            k1 = rt / mxn;
            float mvn = fmaxf(fabsf(rt), EPSV);
            if (mvn > MAXN) k1 *= MAXN / mvn;
            float cn = fminf(mvn, MAXN);
            x2s = cn * cn;
            xy  = k1 * sh;
        } else { k1 = 0.0f; x2s = 0.0f; xy = 0.0f; }
        float ca = 1.0f + 2.0f * xy + y2;
        float cb = 1.0f - x2s;
        float den = fmaxf(1.0f + 2.0f * xy + x2s * y2, EPSV);
        float hn2 = ca*ca*x2s + 2.0f*ca*cb*xy + cb*cb*y2;
        float hn = fmaxf(sqrtf(hn2) / den, EPSV);
        float hs = 1.0f;
        if (hn > MAXN) { hs = MAXN / hn; hn = MAXN; }
        float lam = artanh_(hn) / hn;
        P[r] = lam * hs * ca * k1 / den;
        Q[r] = lam * hs * cb / den;
    }
#pragma unroll
    for (int r = 0; r < 4; ++r) {
        int ri = nodeBase + q * 4 + r;
        if (ri < N) {
            float* orow = agg + (size_t)ri * 64 + m;
            orow[ 0] = P[r] * acc0[r] + Q[r] * hbv[0];
            orow[16] = P[r] * acc1[r] + Q[r] * hbv[1];
            orow[32] = P[r] * acc2[r] + Q[r] * hbv[2];
            orow[48] = P[r] * acc3[r] + Q[r] * hbv[3];
        }
    }
}

// ===== gather #2 + final HypAct fused; 4-way ILP =====
__global__ __launch_bounds__(256) void hg9_gather_out(
    const int* __restrict__ row_start, const int2* __restrict__ csr,
    const float* __restrict__ xt2, float* __restrict__ out, int N) {
    const int lane = threadIdx.x & 63, wv = threadIdx.x >> 6;
    const int d = blockIdx.x * 4 + wv;
    if (d >= N) return;
    const int n0 = row_start[d], n1 = row_start[d + 1];
    float acc0 = 0.f, acc1 = 0.f, acc2 = 0.f, acc3 = 0.f;
    for (int base = n0; base < n1; base += 64) {
        int cnt = n1 - base; if (cnt > 64) cnt = 64;
        int sL = 0; float wL = 0.0f;
        if (lane < cnt) { int2 rec = csr[base + lane]; sL = rec.x; wL = i2f(rec.y); }
        int j = 0;
        for (; j + 4 <= cnt; j += 4) {
            int s0 = __shfl(sL, j),     s1 = __shfl(sL, j + 1);
            int s2 = __shfl(sL, j + 2), s3 = __shfl(sL, j + 3);
            float w0 = __shfl(wL, j),     w1 = __shfl(wL, j + 1);
            float w2 = __shfl(wL, j + 2), w3 = __shfl(wL, j + 3);
            acc0 = fmaf(w0, xt2[(size_t)s0 * 64 + lane], acc0);
            acc1 = fmaf(w1, xt2[(size_t)s1 * 64 + lane], acc1);
            acc2 = fmaf(w2, xt2[(size_t)s2 * 64 + lane], acc2);
            acc3 = fmaf(w3, xt2[(size_t)s3 * 64 + lane], acc3);
        }
        for (; j < cnt; ++j) {
            int s = __shfl(sL, j);
            float w = __shfl(wL, j);
            acc0 = fmaf(w, xt2[(size_t)s * 64 + lane], acc0);
        }
    }
    float acc = (acc0 + acc1) + (acc2 + acc3);
    float xn;
    float o = agg_transform(acc, &xn);
    out[(size_t)d * 64 + lane] = o;
}

// ===== fallback kernels (round-7 proven, used only if ws too small) =====
__global__ __launch_bounds__(256) void hg9_scatter(
    const int* __restrict__ src, const int* __restrict__ dst,
    const float* __restrict__ ew,
    const float* __restrict__ xt, float* __restrict__ agg, int E)
{
    const int lane = threadIdx.x & 63;
    const long long wid = ((long long)blockIdx.x * blockDim.x + threadIdx.x) >> 6;
    const long long nw = ((long long)gridDim.x * blockDim.x) >> 6;
    for (long long e = wid; e < E; e += nw) {
        int s = src[e], d = dst[e];
        atomicAdd(&agg[(size_t)d * 64 + lane], ew[e] * xt[(size_t)s * 64 + lane]);
    }
}

__global__ __launch_bounds__(256) void hg9_layer2_fb(
    const float* __restrict__ agg,
    const float* __restrict__ W2, const float* __restrict__ b2v,
    float* __restrict__ xt2, int N)
{
    const int lane = threadIdx.x & 63, wv = threadIdx.x >> 6;
    float y2;
    float hb = bias_point(b2v, lane, &y2);
    const int nw = gridDim.x * 4;
    for (int i = blockIdx.x * 4 + wv; i < N; i += nw) {
        float a = agg[(size_t)i * 64 + lane];
        float xn;
        float x2 = agg_transform(a, &xn);
        float acc = 0.0f;
        const float* Wrow = W2 + (size_t)lane * 64;
        for (int s = 0; s < 64; ++s)
            acc = fmaf(__shfl(x2, s), Wrow[s], acc);
        float o = mobius_tail(acc, xn, hb, y2);
        xt2[(size_t)i * 64 + lane] = o;
    }
}

__global__ __launch_bounds__(256) void hg9_final_fb(
    const float* __restrict__ agg, float* __restrict__ out, int N)
{
    const int lane = threadIdx.x & 63, wv = threadIdx.x >> 6;
    const int nw = gridDim.x * 4;
    for (int i = blockIdx.x * 4 + wv; i < N; i += nw) {
        float a = agg[(size_t)i * 64 + lane];
        float xn;
        float o = agg_transform(a, &xn);
        out[(size_t)i * 64 + lane] = o;
    }
}

extern "C" void kernel_launch(void* const* d_in, const int* in_sizes, int n_in,
                              void* d_out, int out_size, void* d_ws, size_t ws_size,
                              hipStream_t stream)
{
    const float* x  = (const float*)d_in[0];
    const int* src  = (const int*)d_in[1];
    const int* dst  = (const int*)d_in[2];
    const float* ew = (const float*)d_in[3];
    const float* W1 = (const float*)d_in[4];
    const float* b1 = (const float*)d_in[5];
    const float* W2 = (const float*)d_in[6];
    const float* b2 = (const float*)d_in[7];

    const int Dd = in_sizes[5];            // 64
    const int Ff = in_sizes[4] / Dd;       // 256
    const int N  = in_sizes[0] / Ff;       // 80000
    const int E  = in_sizes[1];            // 1280000

    float* out  = (float*)d_out;
    float* xt   = (float*)d_out;           // [N,64] layer-1 tangent scratch

    // d_ws: [agg f32 N*64][deg N][row_start N+1][cursor N][pad to 8B][csr int2 E]
    float* agg     = (float*)d_ws;
    int*   deg     = (int*)(agg + (size_t)N * Dd);
    int*   rowst   = deg + N;
    int*   cursor  = rowst + (N + 1);
    size_t csr_off = ((size_t)N * Dd * 4 + (size_t)(3 * N + 1) * 4 + 7) & ~(size_t)7;
    int2*  csr     = (int2*)((char*)d_ws + csr_off);
    const size_t ws_need = csr_off + (size_t)E * 8;
    const bool use_csr = ws_size >= ws_need;

    const int blkT = (N + 63) / 64;        // wave per 16 nodes (layer1/layer2)
    const int blkG = (N + 3) / 4;          // wave per dst node (gathers)
    const int n4   = (N * Dd) / 4;

    hg9_layer1<<<blkT, 256, 0, stream>>>(x, W1, b1, xt, N);
    if (use_csr) {
        hg9_zero_i32   <<<128,  256, 0, stream>>>(deg, N);
        hg9_count      <<<2048, 256, 0, stream>>>(dst, deg, E);
        hg9_scan       <<<1,   1024, 0, stream>>>(deg, rowst, cursor, N);
        hg9_fill       <<<2048, 256, 0, stream>>>(src, dst, ew, cursor, csr, E);
        hg9_gather     <<<blkG, 256, 0, stream>>>(rowst, csr, xt, agg, N);
        hg9_layer2_mfma<<<blkT, 256, 0, stream>>>(agg, W2, b2, N);          // in-place
        hg9_gather_out <<<blkG, 256, 0, stream>>>(rowst, csr, agg, out, N);
    } else {
        hg9_zero     <<<1024,  256, 0, stream>>>(agg, n4);
        hg9_scatter  <<<16384, 256, 0, stream>>>(src, dst, ew, xt, agg, E);
        hg9_layer2_fb<<<2048,  256, 0, stream>>>(agg, W2, b2, xt, N);
        hg9_zero     <<<1024,  256, 0, stream>>>(agg, n4);
        hg9_scatter  <<<16384, 256, 0, stream>>>(src, dst, ew, xt, agg, E);
        hg9_final_fb <<<2048,  256, 0, stream>>>(agg, out, N);
    }
}

// Round 10
// 513.515 us; speedup vs baseline: 2.7649x; 1.0057x over previous
//
#include <hip/hip_runtime.h>

// HGCN forward (2-layer hyperbolic GCN), Poincare ball c=1. fp32 in/out
// (values bf16-grid). Round 10 = round 9 with:
//  (a) fill overlapped with layer1 in one role-split kernel (independent work;
//      fill is latency-bound at VALUBusy=0.3% -- layer1's MFMA hides inside it)
//  (b) tangent tables xt/xt2 stored bf16 (halves gather read volume).
//      Buffers: xtb/xtb2 @ ws+0 (bf16 10.24MB), agg @ d_out (fp32 20.48MB),
//      csr @ ws after meta. All read/write hazards checked (see launch order).
// CSR count/scan, gather ILP, layer2-MFMA epilogue as in round 9 (proven).

#define EPSV 1e-15f
#define MAXN 0.996f   // (1 - 4e-3) / sqrt(c), c = 1

typedef unsigned short bfu;
typedef __attribute__((ext_vector_type(8))) short v8s;   // 8 bf16 (4 VGPRs)
typedef __attribute__((ext_vector_type(4))) float v4f;   // MFMA acc

__device__ __forceinline__ bfu f2b(float f) {   // fp32 -> bf16, RNE
    unsigned int u;
    __builtin_memcpy(&u, &f, sizeof(u));
    u += 0x7fffu + ((u >> 16) & 1u);
    return (bfu)(u >> 16);
}

__device__ __forceinline__ float b2f(bfu s) {
    unsigned int u = ((unsigned int)s) << 16;
    float f;
    __builtin_memcpy(&f, &u, sizeof(f));
    return f;
}

__device__ __forceinline__ v8s cvt8(const float* f) {
    v8s r;
#pragma unroll
    for (int j = 0; j < 8; ++j) r[j] = (short)f2b(f[j]);
    return r;
}

__device__ __forceinline__ float i2f(int i) {
    float f; __builtin_memcpy(&f, &i, sizeof(f)); return f;
}
__device__ __forceinline__ int f2i(float f) {
    int i; __builtin_memcpy(&i, &f, sizeof(i)); return i;
}

__device__ __forceinline__ float wredsum(float v) {
#pragma unroll
    for (int o = 32; o > 0; o >>= 1) v += __shfl_xor(v, o, 64);
    return v;
}

__device__ __forceinline__ float artanh_(float x) {
    x = fminf(fmaxf(x, -1.0f + 1e-7f), 1.0f - 1e-7f);
    return 0.5f * logf((1.0f + x) / (1.0f - x));
}

__device__ __forceinline__ float mobius_tail(float mx, float xn, float hb, float y2) {
    float mxn2 = wredsum(mx * mx);
    unsigned long long nz = __ballot(mx != 0.0f);
    float mxn = fmaxf(sqrtf(mxn2), EPSV);
    float rt = tanhf(mxn / xn * artanh_(xn));
    float mv, x2s;
    if (nz != 0ull) {
        mv = (rt / mxn) * mx;
        float mvn = fmaxf(fabsf(rt), EPSV);
        if (mvn > MAXN) mv *= MAXN / mvn;
        float cn = fminf(mvn, MAXN);
        x2s = cn * cn;
    } else { mv = 0.0f; x2s = 0.0f; }
    float xy = wredsum(mv * hb);
    float ca = 1.0f + 2.0f * xy + y2;
    float cb = 1.0f - x2s;
    float den = fmaxf(1.0f + 2.0f * xy + x2s * y2, EPSV);
    float hj = (ca * mv + cb * hb) / den;
    float hn = fmaxf(sqrtf(wredsum(hj * hj)), EPSV);
    if (hn > MAXN) { hj *= MAXN / hn; hn = MAXN; }
    return (artanh_(hn) / hn) * hj;
}

__device__ __forceinline__ float agg_transform(float a, float* xn_out) {
    float n = fmaxf(sqrtf(wredsum(a * a)), EPSV);
    float th = tanhf(n);
    float g = th / n;
    float nh = fmaxf(th, EPSV);
    if (nh > MAXN) { g *= MAXN / nh; nh = MAXN; }
    float h = g * a;
    float t = fmaxf((artanh_(nh) / nh) * h, 0.0f);
    float n2 = fmaxf(sqrtf(wredsum(t * t)), EPSV);
    float th2 = tanhf(n2);
    float g2 = th2 / n2;
    float nh2 = fmaxf(th2, EPSV);
    if (nh2 > MAXN) { g2 *= MAXN / nh2; nh2 = MAXN; }
    *xn_out = nh2;
    return g2 * t;
}

__device__ __forceinline__ float bias_point(const float* bv, int lane, float* y2) {
    float b = bv[lane];
    float bn = fmaxf(sqrtf(wredsum(b * b)), EPSV);
    float gs = tanhf(bn) / bn;
    float hbn = fmaxf(tanhf(bn), EPSV);
    if (hbn > MAXN) gs *= MAXN / hbn;
    float hb = gs * b;
    *y2 = wredsum(hb * hb);
    return hb;
}

__global__ __launch_bounds__(256) void hgA_zero(float* __restrict__ p, int n4) {
    const float4 z = make_float4(0.f, 0.f, 0.f, 0.f);
    int stride = gridDim.x * blockDim.x;
    for (int i = blockIdx.x * blockDim.x + threadIdx.x; i < n4; i += stride)
        ((float4*)p)[i] = z;
}

// ===== layer1 body (MFMA, proven) -- writes bf16 xt =====
__device__ __forceinline__ void layer1_body(
    int bid, const float* __restrict__ x, const float* __restrict__ W1,
    const float* __restrict__ b1v, bfu* __restrict__ xtb, int N)
{
    const int tid = threadIdx.x, lane = tid & 63, wv = tid >> 6;
    const int nodeBase = (bid * 4 + wv) * 16;
    if (nodeBase >= N) return;

    float y2;
    float hb = bias_point(b1v, lane, &y2);
    float hbv[4];
#pragma unroll
    for (int t = 0; t < 4; ++t) hbv[t] = __shfl(hb, (lane & 15) + 16 * t);

    const int m = lane & 15, q = lane >> 4;
    v4f acc0 = {0,0,0,0}, acc1 = {0,0,0,0}, acc2 = {0,0,0,0}, acc3 = {0,0,0,0};
    float usq = 0.0f;

    const float* arow = x + (size_t)(nodeBase + m) * 256 + q * 8;
#pragma unroll
    for (int s = 0; s < 8; ++s) {
        float af[8];
        *(float4*)(af)     = *(const float4*)(arow + s * 32);
        *(float4*)(af + 4) = *(const float4*)(arow + s * 32 + 4);
#pragma unroll
        for (int j = 0; j < 8; ++j) usq = fmaf(af[j], af[j], usq);
        v8s a = cvt8(af);
        const float* wbase = W1 + (size_t)m * 256 + s * 32 + q * 8;
        float wf[8];
        *(float4*)(wf) = *(const float4*)(wbase);
        *(float4*)(wf + 4) = *(const float4*)(wbase + 4);
        acc0 = __builtin_amdgcn_mfma_f32_16x16x32_bf16(a, cvt8(wf), acc0, 0, 0, 0);
        *(float4*)(wf) = *(const float4*)(wbase + 16 * 256);
        *(float4*)(wf + 4) = *(const float4*)(wbase + 16 * 256 + 4);
        acc1 = __builtin_amdgcn_mfma_f32_16x16x32_bf16(a, cvt8(wf), acc1, 0, 0, 0);
        *(float4*)(wf) = *(const float4*)(wbase + 32 * 256);
        *(float4*)(wf + 4) = *(const float4*)(wbase + 32 * 256 + 4);
        acc2 = __builtin_amdgcn_mfma_f32_16x16x32_bf16(a, cvt8(wf), acc2, 0, 0, 0);
        *(float4*)(wf) = *(const float4*)(wbase + 48 * 256);
        *(float4*)(wf + 4) = *(const float4*)(wbase + 48 * 256 + 4);
        acc3 = __builtin_amdgcn_mfma_f32_16x16x32_bf16(a, cvt8(wf), acc3, 0, 0, 0);
    }
    usq += __shfl_xor(usq, 16, 64);
    usq += __shfl_xor(usq, 32, 64);

    float P[4], Q[4];
#pragma unroll
    for (int r = 0; r < 4; ++r) {
        float s2 = acc0[r]*acc0[r] + acc1[r]*acc1[r] + acc2[r]*acc2[r] + acc3[r]*acc3[r];
        float sh = acc0[r]*hbv[0] + acc1[r]*hbv[1] + acc2[r]*hbv[2] + acc3[r]*hbv[3];
#pragma unroll
        for (int o = 1; o < 16; o <<= 1) {
            s2 += __shfl_xor(s2, o, 64);
            sh += __shfl_xor(sh, o, 64);
        }
        float usq_r = __shfl(usq, q * 4 + r);
        float n  = fmaxf(sqrtf(usq_r), EPSV);
        float th = tanhf(n);
        float gamma = th / n;
        float xn = fmaxf(th, EPSV);
        if (xn > MAXN) { gamma *= MAXN / xn; xn = MAXN; }
        float mxn = fmaxf(gamma * sqrtf(s2), EPSV);
        float rt  = tanhf(mxn / xn * artanh_(xn));
        float k1, x2s, xy;
        if (s2 != 0.0f) {
            k1 = (rt / mxn) * gamma;
            float mvn = fmaxf(fabsf(rt), EPSV);
            if (mvn > MAXN) k1 *= MAXN / mvn;
            float cn = fminf(mvn, MAXN);
            x2s = cn * cn;
            xy  = k1 * sh;
        } else { k1 = 0.0f; x2s = 0.0f; xy = 0.0f; }
        float ca = 1.0f + 2.0f * xy + y2;
        float cb = 1.0f - x2s;
        float den = fmaxf(1.0f + 2.0f * xy + x2s * y2, EPSV);
        float hn2 = ca*ca*x2s + 2.0f*ca*cb*xy + cb*cb*y2;
        float hn = fmaxf(sqrtf(hn2) / den, EPSV);
        float hs = 1.0f;
        if (hn > MAXN) { hs = MAXN / hn; hn = MAXN; }
        float lam = artanh_(hn) / hn;
        P[r] = lam * hs * ca * k1 / den;
        Q[r] = lam * hs * cb / den;
    }
#pragma unroll
    for (int r = 0; r < 4; ++r) {
        bfu* orow = xtb + (size_t)(nodeBase + q * 4 + r) * 64 + m;
        orow[ 0] = f2b(P[r] * acc0[r] + Q[r] * hbv[0]);
        orow[16] = f2b(P[r] * acc1[r] + Q[r] * hbv[1]);
        orow[32] = f2b(P[r] * acc2[r] + Q[r] * hbv[2]);
        orow[48] = f2b(P[r] * acc3[r] + Q[r] * hbv[3]);
    }
}

// ===== CSR build =====
__global__ __launch_bounds__(256) void hgA_zero_i32(int* __restrict__ p, int n) {
    int stride = gridDim.x * blockDim.x;
    for (int i = blockIdx.x * blockDim.x + threadIdx.x; i < n; i += stride) p[i] = 0;
}

__global__ __launch_bounds__(256) void hgA_count(
    const int* __restrict__ dst, int* __restrict__ deg, int E) {
    int stride = gridDim.x * blockDim.x;
    for (int e = blockIdx.x * blockDim.x + threadIdx.x; e < E; e += stride)
        atomicAdd(&deg[dst[e]], 1);
}

__global__ __launch_bounds__(1024) void hgA_scan(
    const int* __restrict__ deg, int* __restrict__ row_start,
    int* __restrict__ cursor, int N) {
    __shared__ int wsum[16];
    __shared__ int srun;
    const int tid = threadIdx.x, lane = tid & 63, wv = tid >> 6;
    if (tid == 0) srun = 0;
    __syncthreads();
    for (int base = 0; base < N; base += 1024) {
        int i = base + tid;
        int v = (i < N) ? deg[i] : 0;
        int incl = v;
#pragma unroll
        for (int o = 1; o < 64; o <<= 1) {
            int nbr = __shfl_up(incl, o, 64);
            if (lane >= o) incl += nbr;
        }
        if (lane == 63) wsum[wv] = incl;
        __syncthreads();
        int add = 0;
#pragma unroll
        for (int w = 0; w < 16; ++w) { int s = wsum[w]; if (w < wv) add += s; }
        int excl = srun + add + incl - v;
        if (i < N) { row_start[i] = excl; cursor[i] = excl; }
        __syncthreads();
        if (tid == 1023) srun += add + incl;
        __syncthreads();
    }
    if (tid == 0) row_start[N] = srun;
}

// ===== fused: fill (blocks [0,fillBlocks)) || layer1 (rest) =====
__global__ __launch_bounds__(256) void hgA_fill_layer1(
    const int* __restrict__ src, const int* __restrict__ dst,
    const float* __restrict__ ew, int* __restrict__ cursor,
    int2* __restrict__ csr, int E, int fillBlocks,
    const float* __restrict__ x, const float* __restrict__ W1,
    const float* __restrict__ b1v, bfu* __restrict__ xtb, int N)
{
    const int b = blockIdx.x;
    if (b < fillBlocks) {
        int stride = fillBlocks * blockDim.x;
        for (int e = b * blockDim.x + threadIdx.x; e < E; e += stride) {
            int d = dst[e];
            int slot = atomicAdd(&cursor[d], 1);
            csr[slot] = make_int2(src[e], f2i(ew[e]));
        }
    } else {
        layer1_body(b - fillBlocks, x, W1, b1v, xtb, N);
    }
}

// ===== gather #1: agg[d] = sum w*xtb[src] (bf16 table, 4-way ILP) =====
__global__ __launch_bounds__(256) void hgA_gather(
    const int* __restrict__ row_start, const int2* __restrict__ csr,
    const bfu* __restrict__ xtb, float* __restrict__ agg, int N) {
    const int lane = threadIdx.x & 63, wv = threadIdx.x >> 6;
    const int d = blockIdx.x * 4 + wv;
    if (d >= N) return;
    const int n0 = row_start[d], n1 = row_start[d + 1];
    float acc0 = 0.f, acc1 = 0.f, acc2 = 0.f, acc3 = 0.f;
    for (int base = n0; base < n1; base += 64) {
        int cnt = n1 - base; if (cnt > 64) cnt = 64;
        int sL = 0; float wL = 0.0f;
        if (lane < cnt) { int2 rec = csr[base + lane]; sL = rec.x; wL = i2f(rec.y); }
        int j = 0;
        for (; j + 4 <= cnt; j += 4) {
            int s0 = __shfl(sL, j),     s1 = __shfl(sL, j + 1);
            int s2 = __shfl(sL, j + 2), s3 = __shfl(sL, j + 3);
            float w0 = __shfl(wL, j),     w1 = __shfl(wL, j + 1);
            float w2 = __shfl(wL, j + 2), w3 = __shfl(wL, j + 3);
            acc0 = fmaf(w0, b2f(xtb[(size_t)s0 * 64 + lane]), acc0);
            acc1 = fmaf(w1, b2f(xtb[(size_t)s1 * 64 + lane]), acc1);
            acc2 = fmaf(w2, b2f(xtb[(size_t)s2 * 64 + lane]), acc2);
            acc3 = fmaf(w3, b2f(xtb[(size_t)s3 * 64 + lane]), acc3);
        }
        for (; j < cnt; ++j) {
            int s = __shfl(sL, j);
            float w = __shfl(wL, j);
            acc0 = fmaf(w, b2f(xtb[(size_t)s * 64 + lane]), acc0);
        }
    }
    agg[(size_t)d * 64 + lane] = (acc0 + acc1) + (acc2 + acc3);
}

// ===== layer 2: MFMA fused HypAct+matvec+tail; agg(d_out) -> xtb2(ws, bf16) =====
__global__ __launch_bounds__(256) void hgA_layer2_mfma(
    const float* __restrict__ agg,   // [N,64] fp32 (d_out)
    const float* __restrict__ W2,    // [64,64] row-major
    const float* __restrict__ b2v,   // [64]
    bfu* __restrict__ xtb2, int N)   // [N,64] bf16 (ws)
{
    const int tid = threadIdx.x, lane = tid & 63, wv = tid >> 6;
    const int nodeBase = (blockIdx.x * 4 + wv) * 16;
    if (nodeBase >= N) return;

    float y2;
    float hb = bias_point(b2v, lane, &y2);
    float hbv[4];
#pragma unroll
    for (int t = 0; t < 4; ++t) hbv[t] = __shfl(hb, (lane & 15) + 16 * t);

    const int m = lane & 15, q = lane >> 4;
    const bool rowok = (nodeBase + m) < N;

    float af0[8], af1[8];
    const float* arow = agg + (size_t)(nodeBase + m) * 64 + q * 8;
    if (rowok) {
        *(float4*)(af0)     = *(const float4*)(arow);
        *(float4*)(af0 + 4) = *(const float4*)(arow + 4);
        *(float4*)(af1)     = *(const float4*)(arow + 32);
        *(float4*)(af1 + 4) = *(const float4*)(arow + 36);
    } else {
#pragma unroll
        for (int j = 0; j < 8; ++j) { af0[j] = 0.0f; af1[j] = 0.0f; }
    }
    float asq = 0.0f;
#pragma unroll
    for (int j = 0; j < 8; ++j) {
        asq = fmaf(af0[j], af0[j], asq);
        asq = fmaf(af1[j], af1[j], asq);
    }
    asq += __shfl_xor(asq, 16, 64);
    asq += __shfl_xor(asq, 32, 64);

    float n  = fmaxf(sqrtf(asq), EPSV);
    float th = tanhf(n);
    float g  = th / n;
    float nh = fmaxf(th, EPSV);
    if (nh > MAXN) { g *= MAXN / nh; nh = MAXN; }
    float lamg = (artanh_(nh) / nh) * g;
    float t0[8], t1[8], tsq = 0.0f;
#pragma unroll
    for (int j = 0; j < 8; ++j) {
        t0[j] = fmaxf(lamg * af0[j], 0.0f);
        t1[j] = fmaxf(lamg * af1[j], 0.0f);
        tsq = fmaf(t0[j], t0[j], tsq);
        tsq = fmaf(t1[j], t1[j], tsq);
    }
    tsq += __shfl_xor(tsq, 16, 64);
    tsq += __shfl_xor(tsq, 32, 64);
    float n2  = fmaxf(sqrtf(tsq), EPSV);
    float th2 = tanhf(n2);
    float g2  = th2 / n2;
    float nh2 = fmaxf(th2, EPSV);
    if (nh2 > MAXN) { g2 *= MAXN / nh2; nh2 = MAXN; }
    float xn_m = nh2;
    float x0[8], x1[8];
#pragma unroll
    for (int j = 0; j < 8; ++j) { x0[j] = g2 * t0[j]; x1[j] = g2 * t1[j]; }
    v8s a0 = cvt8(x0), a1 = cvt8(x1);

    v4f acc0 = {0,0,0,0}, acc1 = {0,0,0,0}, acc2 = {0,0,0,0}, acc3 = {0,0,0,0};
    {
        float wf[8];
        const float* wb;
        wb = W2 + (size_t)(m     ) * 64 + q * 8;
        *(float4*)(wf) = *(const float4*)(wb);     *(float4*)(wf+4) = *(const float4*)(wb+4);
        acc0 = __builtin_amdgcn_mfma_f32_16x16x32_bf16(a0, cvt8(wf), acc0, 0, 0, 0);
        *(float4*)(wf) = *(const float4*)(wb+32);  *(float4*)(wf+4) = *(const float4*)(wb+36);
        acc0 = __builtin_amdgcn_mfma_f32_16x16x32_bf16(a1, cvt8(wf), acc0, 0, 0, 0);
        wb = W2 + (size_t)(m + 16) * 64 + q * 8;
        *(float4*)(wf) = *(const float4*)(wb);     *(float4*)(wf+4) = *(const float4*)(wb+4);
        acc1 = __builtin_amdgcn_mfma_f32_16x16x32_bf16(a0, cvt8(wf), acc1, 0, 0, 0);
        *(float4*)(wf) = *(const float4*)(wb+32);  *(float4*)(wf+4) = *(const float4*)(wb+36);
        acc1 = __builtin_amdgcn_mfma_f32_16x16x32_bf16(a1, cvt8(wf), acc1, 0, 0, 0);
        wb = W2 + (size_t)(m + 32) * 64 + q * 8;
        *(float4*)(wf) = *(const float4*)(wb);     *(float4*)(wf+4) = *(const float4*)(wb+4);
        acc2 = __builtin_amdgcn_mfma_f32_16x16x32_bf16(a0, cvt8(wf), acc2, 0, 0, 0);
        *(float4*)(wf) = *(const float4*)(wb+32);  *(float4*)(wf+4) = *(const float4*)(wb+36);
        acc2 = __builtin_amdgcn_mfma_f32_16x16x32_bf16(a1, cvt8(wf), acc2, 0, 0, 0);
        wb = W2 + (size_t)(m + 48) * 64 + q * 8;
        *(float4*)(wf) = *(const float4*)(wb);     *(float4*)(wf+4) = *(const float4*)(wb+4);
        acc3 = __builtin_amdgcn_mfma_f32_16x16x32_bf16(a0, cvt8(wf), acc3, 0, 0, 0);
        *(float4*)(wf) = *(const float4*)(wb+32);  *(float4*)(wf+4) = *(const float4*)(wb+36);
        acc3 = __builtin_amdgcn_mfma_f32_16x16x32_bf16(a1, cvt8(wf), acc3, 0, 0, 0);
    }

    float P[4], Q[4];
#pragma unroll
    for (int r = 0; r < 4; ++r) {
        float s2 = acc0[r]*acc0[r] + acc1[r]*acc1[r] + acc2[r]*acc2[r] + acc3[r]*acc3[r];
        float sh = acc0[r]*hbv[0] + acc1[r]*hbv[1] + acc2[r]*hbv[2] + acc3[r]*hbv[3];
#pragma unroll
        for (int o = 1; o < 16; o <<= 1) {
            s2 += __shfl_xor(s2, o, 64);
            sh += __shfl_xor(sh, o, 64);
        }
        float xn = __shfl(xn_m, q * 4 + r);
        float mxn = fmaxf(sqrtf(s2), EPSV);
        float rt  = tanhf(mxn / xn * artanh_(xn));
        float k1, x2s, xy;
        if (s2 != 0.0f) {
            k1 = rt / mxn;
            float mvn = fmaxf(fabsf(rt), EPSV);
            if (mvn > MAXN) k1 *= MAXN / mvn;
            float cn = fminf(mvn, MAXN);
            x2s = cn * cn;
            xy  = k1 * sh;
        } else { k1 = 0.0f; x2s = 0.0f; xy = 0.0f; }
        float ca = 1.0f + 2.0f * xy + y2;
        float cb = 1.0f - x2s;
        float den = fmaxf(1.0f + 2.0f * xy + x2s * y2, EPSV);
        float hn2 = ca*ca*x2s + 2.0f*ca*cb*xy + cb*cb*y2;
        float hn = fmaxf(sqrtf(hn2) / den, EPSV);
        float hs = 1.0f;
        if (hn > MAXN) { hs = MAXN / hn; hn = MAXN; }
        float lam = artanh_(hn) / hn;
        P[r] = lam * hs * ca * k1 / den;
        Q[r] = lam * hs * cb / den;
    }
#pragma unroll
    for (int r = 0; r < 4; ++r) {
        int ri = nodeBase + q * 4 + r;
        if (ri < N) {
            bfu* orow = xtb2 + (size_t)ri * 64 + m;
            orow[ 0] = f2b(P[r] * acc0[r] + Q[r] * hbv[0]);
            orow[16] = f2b(P[r] * acc1[r] + Q[r] * hbv[1]);
            orow[32] = f2b(P[r] * acc2[r] + Q[r] * hbv[2]);
            orow[48] = f2b(P[r] * acc3[r] + Q[r] * hbv[3]);
        }
    }
}

// ===== gather #2 + final HypAct fused (bf16 table) =====
__global__ __launch_bounds__(256) void hgA_gather_out(
    const int* __restrict__ row_start, const int2* __restrict__ csr,
    const bfu* __restrict__ xtb2, float* __restrict__ out, int N) {
    const int lane = threadIdx.x & 63, wv = threadIdx.x >> 6;
    const int d = blockIdx.x * 4 + wv;
    if (d >= N) return;
    const int n0 = row_start[d], n1 = row_start[d + 1];
    float acc0 = 0.f, acc1 = 0.f, acc2 = 0.f, acc3 = 0.f;
    for (int base = n0; base < n1; base += 64) {
        int cnt = n1 - base; if (cnt > 64) cnt = 64;
        int sL = 0; float wL = 0.0f;
        if (lane < cnt) { int2 rec = csr[base + lane]; sL = rec.x; wL = i2f(rec.y); }
        int j = 0;
        for (; j + 4 <= cnt; j += 4) {
            int s0 = __shfl(sL, j),     s1 = __shfl(sL, j + 1);
            int s2 = __shfl(sL, j + 2), s3 = __shfl(sL, j + 3);
            float w0 = __shfl(wL, j),     w1 = __shfl(wL, j + 1);
            float w2 = __shfl(wL, j + 2), w3 = __shfl(wL, j + 3);
            acc0 = fmaf(w0, b2f(xtb2[(size_t)s0 * 64 + lane]), acc0);
            acc1 = fmaf(w1, b2f(xtb2[(size_t)s1 * 64 + lane]), acc1);
            acc2 = fmaf(w2, b2f(xtb2[(size_t)s2 * 64 + lane]), acc2);
            acc3 = fmaf(w3, b2f(xtb2[(size_t)s3 * 64 + lane]), acc3);
        }
        for (; j < cnt; ++j) {
            int s = __shfl(sL, j);
            float w = __shfl(wL, j);
            acc0 = fmaf(w, b2f(xtb2[(size_t)s * 64 + lane]), acc0);
        }
    }
    float acc = (acc0 + acc1) + (acc2 + acc3);
    float xn;
    float o = agg_transform(acc, &xn);
    out[(size_t)d * 64 + lane] = o;
}

// ===== fallback kernels (round-9 path, used only if ws too small) =====
__global__ __launch_bounds__(256) void hgA_layer1_fp32(
    const float* __restrict__ x, const float* __restrict__ W1,
    const float* __restrict__ b1v, float* __restrict__ xt, int N)
{
    // wave-per-16-nodes MFMA writing fp32 (for the fallback's fp32 xt in d_out)
    const int tid = threadIdx.x, lane = tid & 63, wv = tid >> 6;
    const int nodeBase = (blockIdx.x * 4 + wv) * 16;
    if (nodeBase >= N) return;
    float y2;
    float hb = bias_point(b1v, lane, &y2);
    float hbv[4];
#pragma unroll
    for (int t = 0; t < 4; ++t) hbv[t] = __shfl(hb, (lane & 15) + 16 * t);
    const int m = lane & 15, q = lane >> 4;
    v4f acc0 = {0,0,0,0}, acc1 = {0,0,0,0}, acc2 = {0,0,0,0}, acc3 = {0,0,0,0};
    float usq = 0.0f;
    const float* arow = x + (size_t)(nodeBase + m) * 256 + q * 8;
#pragma unroll
    for (int s = 0; s < 8; ++s) {
        float af[8];
        *(float4*)(af)     = *(const float4*)(arow + s * 32);
        *(float4*)(af + 4) = *(const float4*)(arow + s * 32 + 4);
#pragma unroll
        for (int j = 0; j < 8; ++j) usq = fmaf(af[j], af[j], usq);
        v8s a = cvt8(af);
        const float* wbase = W1 + (size_t)m * 256 + s * 32 + q * 8;
        float wf[8];
        *(float4*)(wf) = *(const float4*)(wbase);  *(float4*)(wf+4) = *(const float4*)(wbase+4);
        acc0 = __builtin_amdgcn_mfma_f32_16x16x32_bf16(a, cvt8(wf), acc0, 0, 0, 0);
        *(float4*)(wf) = *(const float4*)(wbase+16*256); *(float4*)(wf+4) = *(const float4*)(wbase+16*256+4);
        acc1 = __builtin_amdgcn_mfma_f32_16x16x32_bf16(a, cvt8(wf), acc1, 0, 0, 0);
        *(float4*)(wf) = *(const float4*)(wbase+32*256); *(float4*)(wf+4) = *(const float4*)(wbase+32*256+4);
        acc2 = __builtin_amdgcn_mfma_f32_16x16x32_bf16(a, cvt8(wf), acc2, 0, 0, 0);
        *(float4*)(wf) = *(const float4*)(wbase+48*256); *(float4*)(wf+4) = *(const float4*)(wbase+48*256+4);
        acc3 = __builtin_amdgcn_mfma_f32_16x16x32_bf16(a, cvt8(wf), acc3, 0, 0, 0);
    }
    usq += __shfl_xor(usq, 16, 64);
    usq += __shfl_xor(usq, 32, 64);
    float P[4], Q[4];
#pragma unroll
    for (int r = 0; r < 4; ++r) {
        float s2 = acc0[r]*acc0[r] + acc1[r]*acc1[r] + acc2[r]*acc2[r] + acc3[r]*acc3[r];
        float sh = acc0[r]*hbv[0] + acc1[r]*hbv[1] + acc2[r]*hbv[2] + acc3[r]*hbv[3];
#pragma unroll
        for (int o = 1; o < 16; o <<= 1) { s2 += __shfl_xor(s2, o, 64); sh += __shfl_xor(sh, o, 64); }
        float usq_r = __shfl(usq, q * 4 + r);
        float n  = fmaxf(sqrtf(usq_r), EPSV);
        float th = tanhf(n);
        float gamma = th / n;
        float xn = fmaxf(th, EPSV);
        if (xn > MAXN) { gamma *= MAXN / xn; xn = MAXN; }
        float mxn = fmaxf(gamma * sqrtf(s2), EPSV);
        float rt  = tanhf(mxn / xn * artanh_(xn));
        float k1, x2s, xy;
        if (s2 != 0.0f) {
            k1 = (rt / mxn) * gamma;
            float mvn = fmaxf(fabsf(rt), EPSV);
            if (mvn > MAXN) k1 *= MAXN / mvn;
            float cn = fminf(mvn, MAXN);
            x2s = cn * cn; xy = k1 * sh;
        } else { k1 = 0.0f; x2s = 0.0f; xy = 0.0f; }
        float ca = 1.0f + 2.0f * xy + y2;
        float cb = 1.0f - x2s;
        float den = fmaxf(1.0f + 2.0f * xy + x2s * y2, EPSV);
        float hn2 = ca*ca*x2s + 2.0f*ca*cb*xy + cb*cb*y2;
        float hn = fmaxf(sqrtf(hn2) / den, EPSV);
        float hs = 1.0f;
        if (hn > MAXN) { hs = MAXN / hn; hn = MAXN; }
        float lam = artanh_(hn) / hn;
        P[r] = lam * hs * ca * k1 / den;
        Q[r] = lam * hs * cb / den;
    }
#pragma unroll
    for (int r = 0; r < 4; ++r) {
        float* orow = xt + (size_t)(nodeBase + q * 4 + r) * 64 + m;
        orow[ 0] = P[r] * acc0[r] + Q[r] * hbv[0];
        orow[16] = P[r] * acc1[r] + Q[r] * hbv[1];
        orow[32] = P[r] * acc2[r] + Q[r] * hbv[2];
        orow[48] = P[r] * acc3[r] + Q[r] * hbv[3];
    }
}

__global__ __launch_bounds__(256) void hgA_scatter(
    const int* __restrict__ src, const int* __restrict__ dst,
    const float* __restrict__ ew,
    const float* __restrict__ xt, float* __restrict__ agg, int E)
{
    const int lane = threadIdx.x & 63;
    const long long wid = ((long long)blockIdx.x * blockDim.x + threadIdx.x) >> 6;
    const long long nw = ((long long)gridDim.x * blockDim.x) >> 6;
    for (long long e = wid; e < E; e += nw) {
        int s = src[e], d = dst[e];
        atomicAdd(&agg[(size_t)d * 64 + lane], ew[e] * xt[(size_t)s * 64 + lane]);
    }
}

__global__ __launch_bounds__(256) void hgA_layer2_fb(
    const float* __restrict__ agg,
    const float* __restrict__ W2, const float* __restrict__ b2v,
    float* __restrict__ xt2, int N)
{
    const int lane = threadIdx.x & 63, wv = threadIdx.x >> 6;
    float y2;
    float hb = bias_point(b2v, lane, &y2);
    const int nw = gridDim.x * 4;
    for (int i = blockIdx.x * 4 + wv; i < N; i += nw) {
        float a = agg[(size_t)i * 64 + lane];
        float xn;
        float x2 = agg_transform(a, &xn);
        float acc = 0.0f;
        const float* Wrow = W2 + (size_t)lane * 64;
        for (int s = 0; s < 64; ++s)
            acc = fmaf(__shfl(x2, s), Wrow[s], acc);
        float o = mobius_tail(acc, xn, hb, y2);
        xt2[(size_t)i * 64 + lane] = o;
    }
}

__global__ __launch_bounds__(256) void hgA_final_fb(
    const float* __restrict__ agg, float* __restrict__ out, int N)
{
    const int lane = threadIdx.x & 63, wv = threadIdx.x >> 6;
    const int nw = gridDim.x * 4;
    for (int i = blockIdx.x * 4 + wv; i < N; i += nw) {
        float a = agg[(size_t)i * 64 + lane];
        float xn;
        float o = agg_transform(a, &xn);
        out[(size_t)i * 64 + lane] = o;
    }
}

extern "C" void kernel_launch(void* const* d_in, const int* in_sizes, int n_in,
                              void* d_out, int out_size, void* d_ws, size_t ws_size,
                              hipStream_t stream)
{
    const float* x  = (const float*)d_in[0];
    const int* src  = (const int*)d_in[1];
    const int* dst  = (const int*)d_in[2];
    const float* ew = (const float*)d_in[3];
    const float* W1 = (const float*)d_in[4];
    const float* b1 = (const float*)d_in[5];
    const float* W2 = (const float*)d_in[6];
    const float* b2 = (const float*)d_in[7];

    const int Dd = in_sizes[5];            // 64
    const int Ff = in_sizes[4] / Dd;       // 256
    const int N  = in_sizes[0] / Ff;       // 80000
    const int E  = in_sizes[1];            // 1280000

    float* out = (float*)d_out;
    float* agg = (float*)d_out;            // CSR path: fp32 agg lives in d_out

    // ws (CSR path): [xtb/xtb2 bf16 N*64][deg N][rowst N+1][cursor N][pad][csr int2 E]
    bfu*  xtb    = (bfu*)d_ws;
    size_t xtb_b = (size_t)N * Dd * 2;
    int*  deg    = (int*)((char*)d_ws + xtb_b);
    int*  rowst  = deg + N;
    int*  cursor = rowst + (N + 1);
    size_t csr_off = (xtb_b + (size_t)(3 * N + 1) * 4 + 7) & ~(size_t)7;
    int2* csr    = (int2*)((char*)d_ws + csr_off);
    const size_t ws_need = csr_off + (size_t)E * 8;
    const bool use_csr = ws_size >= ws_need;

    const int blkT = (N + 63) / 64;        // wave per 16 nodes
    const int blkG = (N + 3) / 4;          // wave per dst node
    const int fillBlocks = 2048;
    const int n4 = (N * Dd) / 4;

    if (use_csr) {
        hgA_zero_i32   <<<128,  256, 0, stream>>>(deg, N);
        hgA_count      <<<2048, 256, 0, stream>>>(dst, deg, E);
        hgA_scan       <<<1,   1024, 0, stream>>>(deg, rowst, cursor, N);
        hgA_fill_layer1<<<fillBlocks + blkT, 256, 0, stream>>>(
            src, dst, ew, cursor, csr, E, fillBlocks, x, W1, b1, xtb, N);
        hgA_gather     <<<blkG, 256, 0, stream>>>(rowst, csr, xtb, agg, N);
        hgA_layer2_mfma<<<blkT, 256, 0, stream>>>(agg, W2, b2, xtb, N);  // agg(d_out)->xtb(ws)
        hgA_gather_out <<<blkG, 256, 0, stream>>>(rowst, csr, xtb, out, N);
    } else {
        // round-9 fallback: xt fp32 in d_out, agg fp32 in ws
        float* xt_fb  = (float*)d_out;
        float* agg_fb = (float*)d_ws;
        hgA_layer1_fp32<<<blkT, 256, 0, stream>>>(x, W1, b1, xt_fb, N);
        hgA_zero     <<<1024,  256, 0, stream>>>(agg_fb, n4);
        hgA_scatter  <<<16384, 256, 0, stream>>>(src, dst, ew, xt_fb, agg_fb, E);
        hgA_layer2_fb<<<2048,  256, 0, stream>>>(agg_fb, W2, b2, xt_fb, N);
        hgA_zero     <<<1024,  256, 0, stream>>>(agg_fb, n4);
        hgA_scatter  <<<16384, 256, 0, stream>>>(src, dst, ew, xt_fb, agg_fb, E);
        hgA_final_fb <<<2048,  256, 0, stream>>>(agg_fb, out, N);
    }
}